// Round 2
// baseline (18082.542 us; speedup 1.0000x reference)
//
#include <hip/hip_runtime.h>
#include <math.h>

#define DEV_INLINE __device__ __forceinline__

constexpr int B = 32, S = 128, H = 1024, V = 32000, T = 50, L = 3;
constexpr int H2 = 2 * H, H4 = 4 * H;
constexpr int BH = B * H;

// ---- d_out layout (floats): logits (B,T,V) | hT (L,B,H) | cT (L,B,H) | attn (B,T,S)
constexpr size_t HT_OFF   = (size_t)B * T * V;            // 51,200,000
constexpr size_t CT_OFF   = HT_OFF + (size_t)L * B * H;   // +98,304
constexpr size_t ATTN_OFF = CT_OFF + (size_t)L * B * H;   // +98,304

// ---- workspace layout (floats)
constexpr size_t WS_UKEYS = 0;                                // B*S*H
constexpr size_t WS_EMB   = WS_UKEYS + (size_t)B * S * H;     // T*B*H
constexpr size_t WS_H     = WS_EMB + (size_t)T * B * H;       // L*B*H
constexpr size_t WS_C     = WS_H + (size_t)L * B * H;         // L*B*H
constexpr size_t WS_QWA   = WS_C + (size_t)L * B * H;         // B*H
constexpr size_t WS_SCO   = WS_QWA + (size_t)B * H;           // B*S
constexpr size_t WS_XCAT  = WS_SCO + (size_t)B * S;           // B*2H
constexpr size_t WS_GAT   = WS_XCAT + (size_t)B * H2;         // B*4H
constexpr size_t WS_OLN   = WS_GAT + (size_t)B * H4;          // B*H

DEV_INLINE float sigmoidf_(float x) { return 1.f / (1.f + expf(-x)); }

// butterfly: full sum valid in ALL lanes (shfl_down left partials in lanes>0,
// which NaN'd the softmax denominator for masked rows)
DEV_INLINE float wave_sum(float v) {
#pragma unroll
  for (int o = 32; o; o >>= 1) v += __shfl_xor(v, o, 64);
  return v;
}

// block of 256 threads (4 waves)
DEV_INLINE float blk_sum256(float v, float* buf) {
  v = wave_sum(v);
  __syncthreads();
  if ((threadIdx.x & 63) == 0) buf[threadIdx.x >> 6] = v;
  __syncthreads();
  return buf[0] + buf[1] + buf[2] + buf[3];
}

// ---------------------------------------------------------------- state copies
__global__ void k_init(const float* __restrict__ h0, const float* __restrict__ c0,
                       float* __restrict__ hst, float* __restrict__ cst) {
  int idx = blockIdx.x * 256 + threadIdx.x;  // 0 .. 2*L*BH-1
  if (idx < L * BH) hst[idx] = h0[idx];
  else cst[idx - L * BH] = c0[idx - L * BH];
}

__global__ void k_fin(const float* __restrict__ hst, const float* __restrict__ cst,
                      float* __restrict__ out) {
  int idx = blockIdx.x * 256 + threadIdx.x;
  if (idx < L * BH) out[HT_OFF + idx] = hst[idx];
  else out[CT_OFF + (idx - L * BH)] = cst[idx - L * BH];
}

// ------------------------------------------------- Ukeys = enc @ Ua^T + ub
// C[i,j] = sum_k A[i,k]*Bw[j,k] + bias[j].  Tile 128(i) x 64(j), K-chunk 16.
__global__ __launch_bounds__(256) void k_gemm_nt(
    const float* __restrict__ A, const float* __restrict__ Bw,
    const float* __restrict__ bias, float* __restrict__ C, int N, int K) {
  __shared__ float As[16][132];  // [kk][mm]
  __shared__ float Bs[16][68];   // [kk][nn]
  const int i0 = blockIdx.y * 128, j0 = blockIdx.x * 64;
  const int ty = threadIdx.x >> 4, tx = threadIdx.x & 15;
  float acc[8][4] = {};
  for (int k0 = 0; k0 < K; k0 += 16) {
#pragma unroll
    for (int r = 0; r < 8; ++r) {
      int i = threadIdx.x + 256 * r;
      int mm = i >> 4, kk = i & 15;
      As[kk][mm] = A[(size_t)(i0 + mm) * K + k0 + kk];
    }
#pragma unroll
    for (int r = 0; r < 4; ++r) {
      int i = threadIdx.x + 256 * r;
      int nn = i >> 4, kk = i & 15;
      Bs[kk][nn] = Bw[(size_t)(j0 + nn) * K + k0 + kk];
    }
    __syncthreads();
#pragma unroll
    for (int kk = 0; kk < 16; ++kk) {
      float a[8], bb[4];
#pragma unroll
      for (int i = 0; i < 8; ++i) a[i] = As[kk][ty * 8 + i];
#pragma unroll
      for (int j = 0; j < 4; ++j) bb[j] = Bs[kk][tx * 4 + j];
#pragma unroll
      for (int i = 0; i < 8; ++i)
#pragma unroll
        for (int j = 0; j < 4; ++j) acc[i][j] = fmaf(a[i], bb[j], acc[i][j]);
    }
    __syncthreads();
  }
#pragma unroll
  for (int i = 0; i < 8; ++i) {
    size_t row = (size_t)(i0 + ty * 8 + i) * N;
#pragma unroll
    for (int j = 0; j < 4; ++j) {
      int col = j0 + tx * 4 + j;
      C[row + col] = acc[i][j] + bias[col];
    }
  }
}

// --------------------------------------- emb_all[t,b,:] = LN(embedding[tok])
__global__ void k_embln(const float* __restrict__ table, const int* __restrict__ target,
                        const float* __restrict__ g, const float* __restrict__ bta,
                        float* __restrict__ out) {
  __shared__ float rbuf[4];
  int idx = blockIdx.x;  // t*B + b
  int t = idx >> 5, b = idx & 31;
  int tok = (t == 0) ? 0 : target[b * T + (t - 1)];
  const float* e = table + (size_t)tok * H;
  int tid = threadIdx.x;
  float x[4];
#pragma unroll
  for (int r = 0; r < 4; ++r) x[r] = e[r * 256 + tid];
  float m = blk_sum256(x[0] + x[1] + x[2] + x[3], rbuf) * (1.f / H);
  float vs = 0.f;
#pragma unroll
  for (int r = 0; r < 4; ++r) { float d = x[r] - m; vs += d * d; }
  float var = blk_sum256(vs, rbuf) * (1.f / H);
  float rstd = rsqrtf(var + 1e-5f);
  float* o = out + (size_t)idx * H;
#pragma unroll
  for (int r = 0; r < 4; ++r) {
    int h = r * 256 + tid;
    o[h] = (x[r] - m) * rstd * g[h] + bta[h];
  }
}

// ------------------------------------------------------- attention scores
// one wave per (b,s): score = Va . tanh(qwa[b,:] + ukeys[b,s,:]) (+vb)/temp
__global__ void k_scores(const float* __restrict__ qwa, const float* __restrict__ ukeys,
                         const float* __restrict__ va, const float* __restrict__ vb,
                         const float* __restrict__ temp, const int* __restrict__ vlen,
                         float* __restrict__ sco) {
  int lane = threadIdx.x & 63, wid = threadIdx.x >> 6;
  int idx = blockIdx.x * 4 + wid;  // b*S + s
  int b = idx >> 7, s = idx & 127;
  const float* uk = ukeys + (size_t)idx * H;
  const float* q = qwa + (size_t)b * H;
  float a = 0.f;
#pragma unroll
  for (int i = 0; i < 16; ++i) {
    int k = i * 64 + lane;
    a = fmaf(va[k], tanhf(q[k] + uk[k]), a);
  }
  a = wave_sum(a);
  if (lane == 0) {
    float val = (a + vb[0]) / temp[0];
    if (s >= vlen[b]) val = -1e9f;
    sco[idx] = val;
  }
}

// ------------- softmax + attn write + ctx + LN + build xcat = [emb | ctxn]
__global__ void k_smctx(const float* __restrict__ sco, const float* __restrict__ enc,
                        const float* __restrict__ embt, const float* __restrict__ g,
                        const float* __restrict__ bta, float* __restrict__ xcat,
                        float* __restrict__ attn, int t) {
  __shared__ float sw[S];
  __shared__ float rbuf[4];
  int b = blockIdx.x, tid = threadIdx.x;
  if (tid < 64) {
    float v0 = sco[b * S + tid], v1 = sco[b * S + 64 + tid];
    float m = fmaxf(v0, v1);
#pragma unroll
    for (int o = 32; o; o >>= 1) m = fmaxf(m, __shfl_xor(m, o, 64));
    float e0 = expf(v0 - m), e1 = expf(v1 - m);
    float ssum = wave_sum(e0 + e1);   // butterfly: valid in all lanes now
    float inv = 1.f / ssum;
    sw[tid] = e0 * inv;
    sw[64 + tid] = e1 * inv;
  }
  __syncthreads();
  if (tid < S) attn[((size_t)b * T + t) * S + tid] = sw[tid];
  float v[4] = {0.f, 0.f, 0.f, 0.f};
  for (int s2 = 0; s2 < S; ++s2) {
    float wv = sw[s2];
    const float* er = enc + ((size_t)b * S + s2) * H;
#pragma unroll
    for (int r = 0; r < 4; ++r) v[r] = fmaf(wv, er[r * 256 + tid], v[r]);
  }
  float m = blk_sum256(v[0] + v[1] + v[2] + v[3], rbuf) * (1.f / H);
  float vs = 0.f;
#pragma unroll
  for (int r = 0; r < 4; ++r) { float d = v[r] - m; vs += d * d; }
  float var = blk_sum256(vs, rbuf) * (1.f / H);
  float rstd = rsqrtf(var + 1e-5f);
  float* xr = xcat + (size_t)b * H2;
#pragma unroll
  for (int r = 0; r < 4; ++r) {
    int h = r * 256 + tid;
    xr[H + h] = (v[r] - m) * rstd * g[h] + bta[h];
    xr[h] = embt[(size_t)b * H + h];
  }
}

// ----------------------------------------------------------- skinny GEMM
// out[m, j] = sum_k x1[m,k]*W1[j,k] + sum_k x2[m,k]*W2[j,k] + b1[j] + b2[j]
// m in [0,32). 512 threads / block, 16 j per block. K-chunk 128 staged in LDS.
// wave (8 per block): j-group = wid>>1 (4 j each), m-half = wid&1 (16 m each).
__global__ __launch_bounds__(512) void k_skinny(
    const float* __restrict__ x1, const float* __restrict__ W1, int K1,
    const float* __restrict__ x2, const float* __restrict__ W2, int K2,
    const float* __restrict__ b1, const float* __restrict__ b2,
    float* __restrict__ out, int obstride) {
  __shared__ float xs[32][130];
  __shared__ float wsm[16][130];
  const int tid = threadIdx.x, lane = tid & 63, wid = tid >> 6;
  const int gj = wid >> 1;            // 0..3
  const int m0 = (wid & 1) * 16;
  const int jb = blockIdx.x * 16;
  float acc[4][16];
#pragma unroll
  for (int jj = 0; jj < 4; ++jj)
#pragma unroll
    for (int mm = 0; mm < 16; ++mm) acc[jj][mm] = 0.f;

  for (int ph = 0; ph < 2; ++ph) {
    const float* x = ph ? x2 : x1;
    const float* W = ph ? W2 : W1;
    const int K = ph ? K2 : K1;
    if (K == 0) continue;
    for (int k0 = 0; k0 < K; k0 += 128) {
      __syncthreads();
#pragma unroll
      for (int r = 0; r < 8; ++r) {  // stage x: 32x128
        int i = tid + 512 * r;
        int m = i >> 7, kk = i & 127;
        xs[m][kk] = x[(size_t)m * K + k0 + kk];
      }
#pragma unroll
      for (int r = 0; r < 4; ++r) {  // stage W: 16x128
        int i = tid + 512 * r;
        int j = i >> 7, kk = i & 127;
        wsm[j][kk] = W[(size_t)(jb + j) * K + k0 + kk];
      }
      __syncthreads();
      float2 wv[4];
#pragma unroll
      for (int jj = 0; jj < 4; ++jj)
        wv[jj] = *(const float2*)&wsm[gj * 4 + jj][2 * lane];
#pragma unroll
      for (int mm = 0; mm < 16; ++mm) {
        float2 xv = *(const float2*)&xs[m0 + mm][2 * lane];
#pragma unroll
        for (int jj = 0; jj < 4; ++jj) {
          acc[jj][mm] = fmaf(wv[jj].x, xv.x, acc[jj][mm]);
          acc[jj][mm] = fmaf(wv[jj].y, xv.y, acc[jj][mm]);
        }
      }
    }
  }
#pragma unroll
  for (int jj = 0; jj < 4; ++jj) {
    int j = jb + gj * 4 + jj;
    float bsum = (b1 ? b1[j] : 0.f) + (b2 ? b2[j] : 0.f);
#pragma unroll
    for (int mm = 0; mm < 16; ++mm) {
      float a = acc[jj][mm];
#pragma unroll
      for (int o = 32; o; o >>= 1) a += __shfl_down(a, o, 64);
      if (lane == 0) out[(size_t)(m0 + mm) * obstride + j] = a + bsum;
    }
  }
}

// ------------------------------------------------------------- LSTM cell
__global__ void k_cell(const float* __restrict__ gat, float* __restrict__ cl,
                       float* __restrict__ hl) {
  int idx = blockIdx.x * 256 + threadIdx.x;  // b*H + k
  int b = idx >> 10, k = idx & 1023;
  const float* gb = gat + (size_t)b * H4;
  float i_ = gb[k], f_ = gb[H + k], g_ = gb[2 * H + k], o_ = gb[3 * H + k];
  float cn = sigmoidf_(f_) * cl[idx] + sigmoidf_(i_) * tanhf(g_);
  float hn = sigmoidf_(o_) * tanhf(cn);
  cl[idx] = cn;
  hl[idx] = hn;
}

// cell for layer 2 fused with output LayerNorm (block per batch)
__global__ void k_cell2ln(const float* __restrict__ gat, float* __restrict__ cl,
                          float* __restrict__ hl, const float* __restrict__ g,
                          const float* __restrict__ bta, float* __restrict__ oln) {
  __shared__ float rbuf[4];
  int b = blockIdx.x, tid = threadIdx.x;
  const float* gb = gat + (size_t)b * H4;
  float hv[4];
#pragma unroll
  for (int r = 0; r < 4; ++r) {
    int k = r * 256 + tid;
    float i_ = gb[k], f_ = gb[H + k], g_ = gb[2 * H + k], o_ = gb[3 * H + k];
    float cn = sigmoidf_(f_) * cl[b * H + k] + sigmoidf_(i_) * tanhf(g_);
    float hn = sigmoidf_(o_) * tanhf(cn);
    cl[b * H + k] = cn;
    hl[b * H + k] = hn;
    hv[r] = hn;
  }
  float m = blk_sum256(hv[0] + hv[1] + hv[2] + hv[3], rbuf) * (1.f / H);
  float vs = 0.f;
#pragma unroll
  for (int r = 0; r < 4; ++r) { float d = hv[r] - m; vs += d * d; }
  float var = blk_sum256(vs, rbuf) * (1.f / H);
  float rstd = rsqrtf(var + 1e-5f);
#pragma unroll
  for (int r = 0; r < 4; ++r) {
    int k = r * 256 + tid;
    oln[b * H + k] = (hv[r] - m) * rstd * g[k] + bta[k];
  }
}

// ---------------------------------------------------------------------------
extern "C" void kernel_launch(void* const* d_in, const int* in_sizes, int n_in,
                              void* d_out, int out_size, void* d_ws, size_t ws_size,
                              hipStream_t stream) {
  (void)in_sizes; (void)n_in; (void)out_size; (void)ws_size;
  const float* enc = (const float*)d_in[0];
  const float* h0 = (const float*)d_in[1];
  const float* c0 = (const float*)d_in[2];
  const int* vlen = (const int*)d_in[3];
  const int* target = (const int*)d_in[4];
  const float* emb_table = (const float*)d_in[5];
  const float* Wa = (const float*)d_in[6];
  const float* ba = (const float*)d_in[7];
  const float* Ua = (const float*)d_in[8];
  const float* ub = (const float*)d_in[9];
  const float* Va = (const float*)d_in[10];
  const float* vb = (const float*)d_in[11];
  const float* temp = (const float*)d_in[12];
  const float* Wih[3] = {(const float*)d_in[13], (const float*)d_in[17], (const float*)d_in[21]};
  const float* Whh[3] = {(const float*)d_in[14], (const float*)d_in[18], (const float*)d_in[22]};
  const float* bih[3] = {(const float*)d_in[15], (const float*)d_in[19], (const float*)d_in[23]};
  const float* bhh[3] = {(const float*)d_in[16], (const float*)d_in[20], (const float*)d_in[24]};
  const float* fcw = (const float*)d_in[25];
  const float* fcb = (const float*)d_in[26];
  const float* eng = (const float*)d_in[27];
  const float* enb = (const float*)d_in[28];
  const float* cng = (const float*)d_in[29];
  const float* cnb = (const float*)d_in[30];
  const float* ong = (const float*)d_in[31];
  const float* onb = (const float*)d_in[32];

  float* ws = (float*)d_ws;
  float* ukeys = ws + WS_UKEYS;
  float* embv = ws + WS_EMB;
  float* hst = ws + WS_H;
  float* cst = ws + WS_C;
  float* qwa = ws + WS_QWA;
  float* sco = ws + WS_SCO;
  float* xcat = ws + WS_XCAT;
  float* gat = ws + WS_GAT;
  float* oln = ws + WS_OLN;
  float* out = (float*)d_out;

  k_init<<<768, 256, 0, stream>>>(h0, c0, hst, cst);
  // Ukeys: M=B*S=4096, N=H, K=H
  k_gemm_nt<<<dim3(H / 64, (B * S) / 128), 256, 0, stream>>>(enc, Ua, ub, ukeys, H, H);
  k_embln<<<T * B, 256, 0, stream>>>(emb_table, target, eng, enb, embv);

  for (int t = 0; t < T; ++t) {
    // qWa = h[2] @ Wa^T + ba  (N=H -> 64 blocks)
    k_skinny<<<H / 16, 512, 0, stream>>>(hst + 2 * BH, Wa, H, nullptr, nullptr, 0,
                                         ba, nullptr, qwa, H);
    k_scores<<<(B * S) / 4, 256, 0, stream>>>(qwa, ukeys, Va, vb, temp, vlen, sco);
    k_smctx<<<B, 256, 0, stream>>>(sco, enc, embv + (size_t)t * BH, cng, cnb, xcat,
                                   out + ATTN_OFF, t);
    // layer 0: x = xcat (K=2H), recurrent h[0]
    k_skinny<<<H4 / 16, 512, 0, stream>>>(xcat, Wih[0], H2, hst, Whh[0], H,
                                          bih[0], bhh[0], gat, H4);
    k_cell<<<BH / 256, 256, 0, stream>>>(gat, cst, hst);
    // layer 1: x = new h[0], recurrent h[1]
    k_skinny<<<H4 / 16, 512, 0, stream>>>(hst, Wih[1], H, hst + BH, Whh[1], H,
                                          bih[1], bhh[1], gat, H4);
    k_cell<<<BH / 256, 256, 0, stream>>>(gat, cst + BH, hst + BH);
    // layer 2: x = new h[1], recurrent h[2]; cell fused with out-LN
    k_skinny<<<H4 / 16, 512, 0, stream>>>(hst + BH, Wih[2], H, hst + 2 * BH, Whh[2], H,
                                          bih[2], bhh[2], gat, H4);
    k_cell2ln<<<B, 256, 0, stream>>>(gat, cst + 2 * BH, hst + 2 * BH, ong, onb, oln);
    // logits: oln @ fc_w^T + fc_b -> d_out[b*T*V + t*V + j]
    k_skinny<<<V / 16, 512, 0, stream>>>(oln, fcw, H, nullptr, nullptr, 0,
                                         fcb, nullptr, out + (size_t)t * V, T * V);
  }
  k_fin<<<768, 256, 0, stream>>>(hst, cst, out);
}

// Round 3
// 6521.004 us; speedup vs baseline: 2.7730x; 2.7730x over previous
//
#include <hip/hip_runtime.h>
#include <math.h>

#define DEV_INLINE __device__ __forceinline__

constexpr int B = 32, S = 128, H = 1024, V = 32000, T = 50, L = 3;
constexpr int H2 = 2 * H, H4 = 4 * H;
constexpr int BH = B * H;

// ---- d_out layout (floats): logits (B,T,V) | hT (L,B,H) | cT (L,B,H) | attn (B,T,S)
constexpr size_t HT_OFF   = (size_t)B * T * V;
constexpr size_t CT_OFF   = HT_OFF + (size_t)L * B * H;
constexpr size_t ATTN_OFF = CT_OFF + (size_t)L * B * H;

// ---- workspace layout (float units; bf16 buffers consume half-slots)
// total = 6,295,552 floats = same footprint as the passing f32 round
constexpr size_t WS_UKEYS = 0;                                 // 4,194,304 f
constexpr size_t WS_EMB   = WS_UKEYS + (size_t)B * S * H;      // 1,638,400 f
constexpr size_t WS_H     = WS_EMB + (size_t)T * B * H;        //    98,304 f
constexpr size_t WS_C     = WS_H + (size_t)L * B * H;          //    98,304 f
constexpr size_t WS_QWA   = WS_C + (size_t)L * B * H;          //    32,768 f
constexpr size_t WS_SCO   = WS_QWA + (size_t)B * H;            //     4,096 f
constexpr size_t WS_GAT   = WS_SCO + (size_t)B * S;            //   131,072 f
constexpr size_t WS_HBF   = WS_GAT + (size_t)B * H4;           //  49,152 f-eq (L*BH ushort)
constexpr size_t WS_XCBF  = WS_HBF + (size_t)(L * BH) / 2;     //  32,768 f-eq (B*2H ushort)
constexpr size_t WS_OLBF  = WS_XCBF + (size_t)(B * H2) / 2;    //  16,384 f-eq (B*H ushort)

typedef __attribute__((ext_vector_type(8))) short short8;
typedef __attribute__((ext_vector_type(4))) float f32x4;

DEV_INLINE float sigmoidf_(float x) { return 1.f / (1.f + expf(-x)); }

DEV_INLINE unsigned short bf16u(float f) {  // RNE f32->bf16 bits
  union { float f; unsigned u; } v; v.f = f;
  unsigned r = v.u + 0x7fffu + ((v.u >> 16) & 1u);
  return (unsigned short)(r >> 16);
}

// butterfly: full sum valid in ALL lanes
DEV_INLINE float wave_sum(float v) {
#pragma unroll
  for (int o = 32; o; o >>= 1) v += __shfl_xor(v, o, 64);
  return v;
}

DEV_INLINE float blk_sum256(float v, float* buf) {
  v = wave_sum(v);
  __syncthreads();
  if ((threadIdx.x & 63) == 0) buf[threadIdx.x >> 6] = v;
  __syncthreads();
  return buf[0] + buf[1] + buf[2] + buf[3];
}

// ---------------------------------------------------------------- state copies
__global__ void k_init(const float* __restrict__ h0, const float* __restrict__ c0,
                       float* __restrict__ hst, float* __restrict__ cst,
                       unsigned short* __restrict__ hbf) {
  int idx = blockIdx.x * 256 + threadIdx.x;
  if (idx < L * BH) { hst[idx] = h0[idx]; hbf[idx] = bf16u(h0[idx]); }
  else cst[idx - L * BH] = c0[idx - L * BH];
}

__global__ void k_fin(const float* __restrict__ hst, const float* __restrict__ cst,
                      float* __restrict__ out) {
  int idx = blockIdx.x * 256 + threadIdx.x;
  if (idx < L * BH) out[HT_OFF + idx] = hst[idx];
  else out[CT_OFF + (idx - L * BH)] = cst[idx - L * BH];
}

// ------------------------------------------------- Ukeys = enc @ Ua^T + ub (f32, one-time)
__global__ __launch_bounds__(256) void k_gemm_nt(
    const float* __restrict__ A, const float* __restrict__ Bw,
    const float* __restrict__ bias, float* __restrict__ C, int N, int K) {
  __shared__ float As[16][132];
  __shared__ float Bs[16][68];
  const int i0 = blockIdx.y * 128, j0 = blockIdx.x * 64;
  const int ty = threadIdx.x >> 4, tx = threadIdx.x & 15;
  float acc[8][4] = {};
  for (int k0 = 0; k0 < K; k0 += 16) {
#pragma unroll
    for (int r = 0; r < 8; ++r) {
      int i = threadIdx.x + 256 * r;
      int mm = i >> 4, kk = i & 15;
      As[kk][mm] = A[(size_t)(i0 + mm) * K + k0 + kk];
    }
#pragma unroll
    for (int r = 0; r < 4; ++r) {
      int i = threadIdx.x + 256 * r;
      int nn = i >> 4, kk = i & 15;
      Bs[kk][nn] = Bw[(size_t)(j0 + nn) * K + k0 + kk];
    }
    __syncthreads();
#pragma unroll
    for (int kk = 0; kk < 16; ++kk) {
      float a[8], bb[4];
#pragma unroll
      for (int i = 0; i < 8; ++i) a[i] = As[kk][ty * 8 + i];
#pragma unroll
      for (int j = 0; j < 4; ++j) bb[j] = Bs[kk][tx * 4 + j];
#pragma unroll
      for (int i = 0; i < 8; ++i)
#pragma unroll
        for (int j = 0; j < 4; ++j) acc[i][j] = fmaf(a[i], bb[j], acc[i][j]);
    }
    __syncthreads();
  }
#pragma unroll
  for (int i = 0; i < 8; ++i) {
    size_t row = (size_t)(i0 + ty * 8 + i) * N;
#pragma unroll
    for (int j = 0; j < 4; ++j) {
      int col = j0 + tx * 4 + j;
      C[row + col] = acc[i][j] + bias[col];
    }
  }
}

// --------------------------------------- emb_all[t,b,:] = LN(embedding[tok])
__global__ void k_embln(const float* __restrict__ table, const int* __restrict__ target,
                        const float* __restrict__ g, const float* __restrict__ bta,
                        float* __restrict__ out) {
  __shared__ float rbuf[4];
  int idx = blockIdx.x;
  int t = idx >> 5, b = idx & 31;
  int tok = (t == 0) ? 0 : target[b * T + (t - 1)];
  const float* e = table + (size_t)tok * H;
  int tid = threadIdx.x;
  float x[4];
#pragma unroll
  for (int r = 0; r < 4; ++r) x[r] = e[r * 256 + tid];
  float m = blk_sum256(x[0] + x[1] + x[2] + x[3], rbuf) * (1.f / H);
  float vs = 0.f;
#pragma unroll
  for (int r = 0; r < 4; ++r) { float d = x[r] - m; vs += d * d; }
  float var = blk_sum256(vs, rbuf) * (1.f / H);
  float rstd = rsqrtf(var + 1e-5f);
  float* o = out + (size_t)idx * H;
#pragma unroll
  for (int r = 0; r < 4; ++r) {
    int h = r * 256 + tid;
    o[h] = (x[r] - m) * rstd * g[h] + bta[h];
  }
}

// ------------------------------------------------------- attention scores
__global__ void k_scores(const float* __restrict__ qwa, const float* __restrict__ ukeys,
                         const float* __restrict__ va, const float* __restrict__ vb,
                         const float* __restrict__ temp, const int* __restrict__ vlen,
                         float* __restrict__ sco) {
  int lane = threadIdx.x & 63, wid = threadIdx.x >> 6;
  int idx = blockIdx.x * 4 + wid;  // b*S + s
  int b = idx >> 7, s = idx & 127;
  const float* uk = ukeys + (size_t)idx * H;
  const float* q = qwa + (size_t)b * H;
  float a = 0.f;
#pragma unroll
  for (int i = 0; i < 16; ++i) {
    int k = i * 64 + lane;
    a = fmaf(va[k], tanhf(q[k] + uk[k]), a);
  }
  a = wave_sum(a);
  if (lane == 0) {
    float val = (a + vb[0]) / temp[0];
    if (s >= vlen[b]) val = -1e9f;
    sco[idx] = val;
  }
}

// ------ softmax + attn write + ctx + LN + build xcat_bf16 = [emb | ctxn]
__global__ void k_smctx(const float* __restrict__ sco, const float* __restrict__ enc,
                        const float* __restrict__ embt, const float* __restrict__ g,
                        const float* __restrict__ bta, unsigned short* __restrict__ xbf,
                        float* __restrict__ attn, int t) {
  __shared__ float sw[S];
  __shared__ float rbuf[4];
  int b = blockIdx.x, tid = threadIdx.x;
  if (tid < 64) {
    float v0 = sco[b * S + tid], v1 = sco[b * S + 64 + tid];
    float m = fmaxf(v0, v1);
#pragma unroll
    for (int o = 32; o; o >>= 1) m = fmaxf(m, __shfl_xor(m, o, 64));
    float e0 = expf(v0 - m), e1 = expf(v1 - m);
    float ssum = wave_sum(e0 + e1);
    float inv = 1.f / ssum;
    sw[tid] = e0 * inv;
    sw[64 + tid] = e1 * inv;
  }
  __syncthreads();
  if (tid < S) attn[((size_t)b * T + t) * S + tid] = sw[tid];
  float v[4] = {0.f, 0.f, 0.f, 0.f};
  for (int s2 = 0; s2 < S; ++s2) {
    float wv = sw[s2];
    const float* er = enc + ((size_t)b * S + s2) * H;
#pragma unroll
    for (int r = 0; r < 4; ++r) v[r] = fmaf(wv, er[r * 256 + tid], v[r]);
  }
  float m = blk_sum256(v[0] + v[1] + v[2] + v[3], rbuf) * (1.f / H);
  float vs = 0.f;
#pragma unroll
  for (int r = 0; r < 4; ++r) { float d = v[r] - m; vs += d * d; }
  float var = blk_sum256(vs, rbuf) * (1.f / H);
  float rstd = rsqrtf(var + 1e-5f);
  unsigned short* xr = xbf + (size_t)b * H2;
#pragma unroll
  for (int r = 0; r < 4; ++r) {
    int h = r * 256 + tid;
    xr[H + h] = bf16u((v[r] - m) * rstd * g[h] + bta[h]);
    xr[h] = bf16u(embt[(size_t)b * H + h]);
  }
}

// ----------------------------------------------------- MFMA skinny GEMM
// out[m,j] = sum_k x1[m,k]*W1[j,k] + sum_k x2[m,k]*W2[j,k] + b1[j] + b2[j]
// M=32, 16 j per block. 256 thr = 4 waves splitting K; x in bf16, W f32->bf16
// in-register. mfma_f32_16x16x32_bf16: A-frag row=lane&15, k=(lane>>4)*8+e;
// B-frag col=lane&15 (W row), same k; D: col(j)=lane&15, row(m)=(lane>>4)*4+r.
__global__ __launch_bounds__(256) void k_mfma_skinny(
    const unsigned short* __restrict__ x1, const float* __restrict__ W1, int K1,
    const unsigned short* __restrict__ x2, const float* __restrict__ W2, int K2,
    const float* __restrict__ b1, const float* __restrict__ b2,
    float* __restrict__ out, int obstride) {
  __shared__ float red[4][32][16];
  const int lane = threadIdx.x & 63, wid = threadIdx.x >> 6;
  const int jb = blockIdx.x * 16;
  const int jl = lane & 15, kg = lane >> 4;
  f32x4 acc0 = {0.f, 0.f, 0.f, 0.f}, acc1 = {0.f, 0.f, 0.f, 0.f};
  const int s1 = K1 >> 5, s2 = K2 >> 5;
  const int per = (s1 + s2) >> 2;  // all totals divisible by 4
  const int send = (wid + 1) * per;
  for (int s = wid * per; s < send; ++s) {
    const unsigned short* x; const float* W; int K, k0;
    if (s < s1) { x = x1; W = W1; K = K1; k0 = s * 32; }
    else       { x = x2; W = W2; K = K2; k0 = (s - s1) * 32; }
    const int ke = k0 + kg * 8;
    const float* wp = W + (size_t)(jb + jl) * K + ke;
    f32x4 w0 = *(const f32x4*)wp;
    f32x4 w1 = *(const f32x4*)(wp + 4);
    short8 bw;
    bw[0] = (short)bf16u(w0[0]); bw[1] = (short)bf16u(w0[1]);
    bw[2] = (short)bf16u(w0[2]); bw[3] = (short)bf16u(w0[3]);
    bw[4] = (short)bf16u(w1[0]); bw[5] = (short)bf16u(w1[1]);
    bw[6] = (short)bf16u(w1[2]); bw[7] = (short)bf16u(w1[3]);
    short8 a0 = *(const short8*)(x + (size_t)jl * K + ke);
    short8 a1 = *(const short8*)(x + (size_t)(16 + jl) * K + ke);
    acc0 = __builtin_amdgcn_mfma_f32_16x16x32_bf16(a0, bw, acc0, 0, 0, 0);
    acc1 = __builtin_amdgcn_mfma_f32_16x16x32_bf16(a1, bw, acc1, 0, 0, 0);
  }
#pragma unroll
  for (int r = 0; r < 4; ++r) {
    red[wid][kg * 4 + r][jl] = acc0[r];
    red[wid][16 + kg * 4 + r][jl] = acc1[r];
  }
  __syncthreads();
  const int tid = threadIdx.x;
#pragma unroll
  for (int u = 0; u < 2; ++u) {
    int oi = tid * 2 + u;  // 0..511
    int m = oi >> 4, j = oi & 15;
    float v = red[0][m][j] + red[1][m][j] + red[2][m][j] + red[3][m][j];
    int jg = jb + j;
    v += (b1 ? b1[jg] : 0.f) + (b2 ? b2[jg] : 0.f);
    out[(size_t)m * obstride + jg] = v;
  }
}

// ------------------------------------------------------------- LSTM cell
__global__ void k_cell(const float* __restrict__ gat, float* __restrict__ cl,
                       float* __restrict__ hl, unsigned short* __restrict__ hbf) {
  int idx = blockIdx.x * 256 + threadIdx.x;  // b*H + k
  int b = idx >> 10, k = idx & 1023;
  const float* gb = gat + (size_t)b * H4;
  float i_ = gb[k], f_ = gb[H + k], g_ = gb[2 * H + k], o_ = gb[3 * H + k];
  float cn = sigmoidf_(f_) * cl[idx] + sigmoidf_(i_) * tanhf(g_);
  float hn = sigmoidf_(o_) * tanhf(cn);
  cl[idx] = cn;
  hl[idx] = hn;
  hbf[idx] = bf16u(hn);
}

// cell for layer 2 fused with output LayerNorm (block per batch)
__global__ void k_cell2ln(const float* __restrict__ gat, float* __restrict__ cl,
                          float* __restrict__ hl, const float* __restrict__ g,
                          const float* __restrict__ bta, unsigned short* __restrict__ olbf,
                          unsigned short* __restrict__ hbf) {
  __shared__ float rbuf[4];
  int b = blockIdx.x, tid = threadIdx.x;
  const float* gb = gat + (size_t)b * H4;
  float hv[4];
#pragma unroll
  for (int r = 0; r < 4; ++r) {
    int k = r * 256 + tid;
    float i_ = gb[k], f_ = gb[H + k], g_ = gb[2 * H + k], o_ = gb[3 * H + k];
    float cn = sigmoidf_(f_) * cl[b * H + k] + sigmoidf_(i_) * tanhf(g_);
    float hn = sigmoidf_(o_) * tanhf(cn);
    cl[b * H + k] = cn;
    hl[b * H + k] = hn;
    hbf[b * H + k] = bf16u(hn);
    hv[r] = hn;
  }
  float m = blk_sum256(hv[0] + hv[1] + hv[2] + hv[3], rbuf) * (1.f / H);
  float vs = 0.f;
#pragma unroll
  for (int r = 0; r < 4; ++r) { float d = hv[r] - m; vs += d * d; }
  float var = blk_sum256(vs, rbuf) * (1.f / H);
  float rstd = rsqrtf(var + 1e-5f);
#pragma unroll
  for (int r = 0; r < 4; ++r) {
    int k = r * 256 + tid;
    olbf[b * H + k] = bf16u((hv[r] - m) * rstd * g[k] + bta[k]);
  }
}

// ---------------------------------------------------------------------------
extern "C" void kernel_launch(void* const* d_in, const int* in_sizes, int n_in,
                              void* d_out, int out_size, void* d_ws, size_t ws_size,
                              hipStream_t stream) {
  (void)in_sizes; (void)n_in; (void)out_size; (void)ws_size;
  const float* enc = (const float*)d_in[0];
  const float* h0 = (const float*)d_in[1];
  const float* c0 = (const float*)d_in[2];
  const int* vlen = (const int*)d_in[3];
  const int* target = (const int*)d_in[4];
  const float* emb_table = (const float*)d_in[5];
  const float* Wa = (const float*)d_in[6];
  const float* ba = (const float*)d_in[7];
  const float* Ua = (const float*)d_in[8];
  const float* ub = (const float*)d_in[9];
  const float* Va = (const float*)d_in[10];
  const float* vb = (const float*)d_in[11];
  const float* temp = (const float*)d_in[12];
  const float* Wih[3] = {(const float*)d_in[13], (const float*)d_in[17], (const float*)d_in[21]};
  const float* Whh[3] = {(const float*)d_in[14], (const float*)d_in[18], (const float*)d_in[22]};
  const float* bih[3] = {(const float*)d_in[15], (const float*)d_in[19], (const float*)d_in[23]};
  const float* bhh[3] = {(const float*)d_in[16], (const float*)d_in[20], (const float*)d_in[24]};
  const float* fcw = (const float*)d_in[25];
  const float* fcb = (const float*)d_in[26];
  const float* eng = (const float*)d_in[27];
  const float* enb = (const float*)d_in[28];
  const float* cng = (const float*)d_in[29];
  const float* cnb = (const float*)d_in[30];
  const float* ong = (const float*)d_in[31];
  const float* onb = (const float*)d_in[32];

  float* ws = (float*)d_ws;
  float* ukeys = ws + WS_UKEYS;
  float* embv = ws + WS_EMB;
  float* hst = ws + WS_H;
  float* cst = ws + WS_C;
  float* qwa = ws + WS_QWA;
  float* sco = ws + WS_SCO;
  float* gat = ws + WS_GAT;
  unsigned short* hbf = (unsigned short*)(ws + WS_HBF);
  unsigned short* xcbf = (unsigned short*)(ws + WS_XCBF);
  unsigned short* olbf = (unsigned short*)(ws + WS_OLBF);
  float* out = (float*)d_out;

  k_init<<<768, 256, 0, stream>>>(h0, c0, hst, cst, hbf);
  k_gemm_nt<<<dim3(H / 64, (B * S) / 128), 256, 0, stream>>>(enc, Ua, ub, ukeys, H, H);
  k_embln<<<T * B, 256, 0, stream>>>(emb_table, target, eng, enb, embv);

  for (int t = 0; t < T; ++t) {
    // qWa = h[2] @ Wa^T + ba
    k_mfma_skinny<<<H / 16, 256, 0, stream>>>(hbf + 2 * BH, Wa, H, nullptr, nullptr, 0,
                                              ba, nullptr, qwa, H);
    k_scores<<<(B * S) / 4, 256, 0, stream>>>(qwa, ukeys, Va, vb, temp, vlen, sco);
    k_smctx<<<B, 256, 0, stream>>>(sco, enc, embv + (size_t)t * BH, cng, cnb, xcbf,
                                   out + ATTN_OFF, t);
    // layer 0: x1 = xcat_bf (K=2H), x2 = h0_bf (K=H)
    k_mfma_skinny<<<H4 / 16, 256, 0, stream>>>(xcbf, Wih[0], H2, hbf, Whh[0], H,
                                               bih[0], bhh[0], gat, H4);
    k_cell<<<BH / 256, 256, 0, stream>>>(gat, cst, hst, hbf);
    // layer 1
    k_mfma_skinny<<<H4 / 16, 256, 0, stream>>>(hbf, Wih[1], H, hbf + BH, Whh[1], H,
                                               bih[1], bhh[1], gat, H4);
    k_cell<<<BH / 256, 256, 0, stream>>>(gat, cst + BH, hst + BH, hbf + BH);
    // layer 2 (cell fused with out-LN, writes oln_bf16)
    k_mfma_skinny<<<H4 / 16, 256, 0, stream>>>(hbf + BH, Wih[2], H, hbf + 2 * BH, Whh[2], H,
                                               bih[2], bhh[2], gat, H4);
    k_cell2ln<<<B, 256, 0, stream>>>(gat, cst + 2 * BH, hst + 2 * BH, ong, onb, olbf,
                                     hbf + 2 * BH);
    // logits: oln_bf @ fc_w^T + fc_b
    k_mfma_skinny<<<V / 16, 256, 0, stream>>>(olbf, fcw, H, nullptr, nullptr, 0,
                                              fcb, nullptr, out + (size_t)t * V, T * V);
  }
  k_fin<<<768, 256, 0, stream>>>(hst, cst, out);
}

// Round 4
// 5791.842 us; speedup vs baseline: 3.1221x; 1.1259x over previous
//
#include <hip/hip_runtime.h>
#include <math.h>

#define DEV_INLINE __device__ __forceinline__

constexpr int B = 32, S = 128, H = 1024, V = 32000, T = 50, L = 3;
constexpr int H2 = 2 * H, H4 = 4 * H;
constexpr int BH = B * H;

// ---- d_out layout (floats): logits (B,T,V) | hT (L,B,H) | cT (L,B,H) | attn (B,T,S)
constexpr size_t HT_OFF   = (size_t)B * T * V;
constexpr size_t CT_OFF   = HT_OFF + (size_t)L * B * H;
constexpr size_t ATTN_OFF = CT_OFF + (size_t)L * B * H;

// ---- workspace layout (float units; bf16 buffers consume half-slots)
constexpr size_t WS_UKEYS = 0;                                 // 4,194,304 f
constexpr size_t WS_EMB   = WS_UKEYS + (size_t)B * S * H;      // 1,638,400 f
constexpr size_t WS_H     = WS_EMB + (size_t)T * B * H;        //    98,304 f
constexpr size_t WS_C     = WS_H + (size_t)L * B * H;          //    98,304 f
constexpr size_t WS_QWA   = WS_C + (size_t)L * B * H;          //    32,768 f
constexpr size_t WS_SCO   = WS_QWA + (size_t)B * H;            //     4,096 f
constexpr size_t WS_GAT   = WS_SCO + (size_t)B * S;            //   131,072 f
constexpr size_t WS_HBF   = WS_GAT + (size_t)B * H4;           //  49,152 f-eq
constexpr size_t WS_XCBF  = WS_HBF + (size_t)(L * BH) / 2;     //  32,768 f-eq
constexpr size_t WS_OLBF  = WS_XCBF + (size_t)(B * H2) / 2;    //  16,384 f-eq
constexpr size_t WS_WBF   = WS_OLBF + (size_t)(B * H) / 2;     // = 6,295,552 f

// bf16 weight region offsets (ushort units from WS_WBF base)
constexpr size_t OW_WA   = 0;                       // 1,048,576
constexpr size_t OW_WIH0 = OW_WA   + (size_t)H * H;         // 8,388,608
constexpr size_t OW_WHH0 = OW_WIH0 + (size_t)H4 * H2;       // 4,194,304
constexpr size_t OW_WIH1 = OW_WHH0 + (size_t)H4 * H;
constexpr size_t OW_WHH1 = OW_WIH1 + (size_t)H4 * H;
constexpr size_t OW_WIH2 = OW_WHH1 + (size_t)H4 * H;
constexpr size_t OW_WHH2 = OW_WIH2 + (size_t)H4 * H;
constexpr size_t OW_FCW  = OW_WHH2 + (size_t)H4 * H;        // 32,768,000
constexpr size_t OW_END  = OW_FCW  + (size_t)V * H;         // 63,176,704
constexpr size_t NEED_WS_BYTES = WS_WBF * 4 + OW_END * 2;   // 151,535,616

typedef __attribute__((ext_vector_type(8))) short short8;
typedef __attribute__((ext_vector_type(4))) float f32x4;
typedef __attribute__((ext_vector_type(4))) unsigned short u16x4;

DEV_INLINE float sigmoidf_(float x) { return 1.f / (1.f + expf(-x)); }

DEV_INLINE unsigned short bf16u(float f) {  // RNE f32->bf16 bits
  union { float f; unsigned u; } v; v.f = f;
  unsigned r = v.u + 0x7fffu + ((v.u >> 16) & 1u);
  return (unsigned short)(r >> 16);
}

DEV_INLINE float wave_sum(float v) {
#pragma unroll
  for (int o = 32; o; o >>= 1) v += __shfl_xor(v, o, 64);
  return v;
}

DEV_INLINE float blk_sum256(float v, float* buf) {
  v = wave_sum(v);
  __syncthreads();
  if ((threadIdx.x & 63) == 0) buf[threadIdx.x >> 6] = v;
  __syncthreads();
  return buf[0] + buf[1] + buf[2] + buf[3];
}

// ---------------------------------------------------------------- state copies
__global__ void k_init(const float* __restrict__ h0, const float* __restrict__ c0,
                       float* __restrict__ hst, float* __restrict__ cst,
                       unsigned short* __restrict__ hbf) {
  int idx = blockIdx.x * 256 + threadIdx.x;
  if (idx < L * BH) { hst[idx] = h0[idx]; hbf[idx] = bf16u(h0[idx]); }
  else cst[idx - L * BH] = c0[idx - L * BH];
}

__global__ void k_fin(const float* __restrict__ hst, const float* __restrict__ cst,
                      float* __restrict__ out) {
  int idx = blockIdx.x * 256 + threadIdx.x;
  if (idx < L * BH) out[HT_OFF + idx] = hst[idx];
  else out[CT_OFF + (idx - L * BH)] = cst[idx - L * BH];
}

// ---------------------------------------------- f32 -> bf16 weight conversion
__global__ void k_cvt(const float* __restrict__ src, unsigned short* __restrict__ dst,
                      int n4) {
  int i = blockIdx.x * 256 + threadIdx.x;
  int stride = gridDim.x * 256;
  for (; i < n4; i += stride) {
    f32x4 v = *(const f32x4*)(src + (size_t)i * 4);
    u16x4 o;
    o[0] = bf16u(v[0]); o[1] = bf16u(v[1]); o[2] = bf16u(v[2]); o[3] = bf16u(v[3]);
    *(u16x4*)(dst + (size_t)i * 4) = o;
  }
}

// ------------------------------------------------- Ukeys = enc @ Ua^T + ub (f32, one-time)
__global__ __launch_bounds__(256) void k_gemm_nt(
    const float* __restrict__ A, const float* __restrict__ Bw,
    const float* __restrict__ bias, float* __restrict__ C, int N, int K) {
  __shared__ float As[16][132];
  __shared__ float Bs[16][68];
  const int i0 = blockIdx.y * 128, j0 = blockIdx.x * 64;
  const int ty = threadIdx.x >> 4, tx = threadIdx.x & 15;
  float acc[8][4] = {};
  for (int k0 = 0; k0 < K; k0 += 16) {
#pragma unroll
    for (int r = 0; r < 8; ++r) {
      int i = threadIdx.x + 256 * r;
      int mm = i >> 4, kk = i & 15;
      As[kk][mm] = A[(size_t)(i0 + mm) * K + k0 + kk];
    }
#pragma unroll
    for (int r = 0; r < 4; ++r) {
      int i = threadIdx.x + 256 * r;
      int nn = i >> 4, kk = i & 15;
      Bs[kk][nn] = Bw[(size_t)(j0 + nn) * K + k0 + kk];
    }
    __syncthreads();
#pragma unroll
    for (int kk = 0; kk < 16; ++kk) {
      float a[8], bb[4];
#pragma unroll
      for (int i = 0; i < 8; ++i) a[i] = As[kk][ty * 8 + i];
#pragma unroll
      for (int j = 0; j < 4; ++j) bb[j] = Bs[kk][tx * 4 + j];
#pragma unroll
      for (int i = 0; i < 8; ++i)
#pragma unroll
        for (int j = 0; j < 4; ++j) acc[i][j] = fmaf(a[i], bb[j], acc[i][j]);
    }
    __syncthreads();
  }
#pragma unroll
  for (int i = 0; i < 8; ++i) {
    size_t row = (size_t)(i0 + ty * 8 + i) * N;
#pragma unroll
    for (int j = 0; j < 4; ++j) {
      int col = j0 + tx * 4 + j;
      C[row + col] = acc[i][j] + bias[col];
    }
  }
}

// --------------------------------------- emb_all[t,b,:] = LN(embedding[tok])
__global__ void k_embln(const float* __restrict__ table, const int* __restrict__ target,
                        const float* __restrict__ g, const float* __restrict__ bta,
                        float* __restrict__ out) {
  __shared__ float rbuf[4];
  int idx = blockIdx.x;
  int t = idx >> 5, b = idx & 31;
  int tok = (t == 0) ? 0 : target[b * T + (t - 1)];
  const float* e = table + (size_t)tok * H;
  int tid = threadIdx.x;
  float x[4];
#pragma unroll
  for (int r = 0; r < 4; ++r) x[r] = e[r * 256 + tid];
  float m = blk_sum256(x[0] + x[1] + x[2] + x[3], rbuf) * (1.f / H);
  float vs = 0.f;
#pragma unroll
  for (int r = 0; r < 4; ++r) { float d = x[r] - m; vs += d * d; }
  float var = blk_sum256(vs, rbuf) * (1.f / H);
  float rstd = rsqrtf(var + 1e-5f);
  float* o = out + (size_t)idx * H;
#pragma unroll
  for (int r = 0; r < 4; ++r) {
    int h = r * 256 + tid;
    o[h] = (x[r] - m) * rstd * g[h] + bta[h];
  }
}

// ------------------------------------------------------- attention scores
__global__ void k_scores(const float* __restrict__ qwa, const float* __restrict__ ukeys,
                         const float* __restrict__ va, const float* __restrict__ vb,
                         const float* __restrict__ temp, const int* __restrict__ vlen,
                         float* __restrict__ sco) {
  int lane = threadIdx.x & 63, wid = threadIdx.x >> 6;
  int idx = blockIdx.x * 4 + wid;  // b*S + s
  int b = idx >> 7, s = idx & 127;
  const float* uk = ukeys + (size_t)idx * H;
  const float* q = qwa + (size_t)b * H;
  float a = 0.f;
#pragma unroll
  for (int i = 0; i < 16; ++i) {
    int k = i * 64 + lane;
    a = fmaf(va[k], tanhf(q[k] + uk[k]), a);
  }
  a = wave_sum(a);
  if (lane == 0) {
    float val = (a + vb[0]) / temp[0];
    if (s >= vlen[b]) val = -1e9f;
    sco[idx] = val;
  }
}

// ------ softmax + attn write + ctx + LN + build xcat_bf16 = [emb | ctxn]
__global__ void k_smctx(const float* __restrict__ sco, const float* __restrict__ enc,
                        const float* __restrict__ embt, const float* __restrict__ g,
                        const float* __restrict__ bta, unsigned short* __restrict__ xbf,
                        float* __restrict__ attn, int t) {
  __shared__ float sw[S];
  __shared__ float rbuf[4];
  int b = blockIdx.x, tid = threadIdx.x;
  if (tid < 64) {
    float v0 = sco[b * S + tid], v1 = sco[b * S + 64 + tid];
    float m = fmaxf(v0, v1);
#pragma unroll
    for (int o = 32; o; o >>= 1) m = fmaxf(m, __shfl_xor(m, o, 64));
    float e0 = expf(v0 - m), e1 = expf(v1 - m);
    float ssum = wave_sum(e0 + e1);
    float inv = 1.f / ssum;
    sw[tid] = e0 * inv;
    sw[64 + tid] = e1 * inv;
  }
  __syncthreads();
  if (tid < S) attn[((size_t)b * T + t) * S + tid] = sw[tid];
  float v[4] = {0.f, 0.f, 0.f, 0.f};
  for (int s2 = 0; s2 < S; ++s2) {
    float wv = sw[s2];
    const float* er = enc + ((size_t)b * S + s2) * H;
#pragma unroll
    for (int r = 0; r < 4; ++r) v[r] = fmaf(wv, er[r * 256 + tid], v[r]);
  }
  float m = blk_sum256(v[0] + v[1] + v[2] + v[3], rbuf) * (1.f / H);
  float vs = 0.f;
#pragma unroll
  for (int r = 0; r < 4; ++r) { float d = v[r] - m; vs += d * d; }
  float var = blk_sum256(vs, rbuf) * (1.f / H);
  float rstd = rsqrtf(var + 1e-5f);
  unsigned short* xr = xbf + (size_t)b * H2;
#pragma unroll
  for (int r = 0; r < 4; ++r) {
    int h = r * 256 + tid;
    xr[H + h] = bf16u((v[r] - m) * rstd * g[h] + bta[h]);
    xr[h] = bf16u(embt[(size_t)b * H + h]);
  }
}

// ----------------------------------------------------- MFMA skinny GEMM (bf16 W)
// out[m,j] = sum_k x[m,k]*Wb[j,k] + bias[j].  M=32, 16 j/block, 4 waves split K.
__global__ __launch_bounds__(256) void k_skinny_bf(
    const unsigned short* __restrict__ x, const unsigned short* __restrict__ Wb, int K,
    const float* __restrict__ bias, float* __restrict__ out, int obstride) {
  __shared__ float red[4][32][16];
  const int lane = threadIdx.x & 63, wid = threadIdx.x >> 6;
  const int jb = blockIdx.x * 16;
  const int jl = lane & 15, kg = lane >> 4;
  f32x4 acc0 = {0.f, 0.f, 0.f, 0.f}, acc1 = {0.f, 0.f, 0.f, 0.f};
  const int per = (K >> 5) >> 2;
  const int send = (wid + 1) * per;
  for (int s = wid * per; s < send; ++s) {
    const int ke = s * 32 + kg * 8;
    short8 bw = *(const short8*)(Wb + (size_t)(jb + jl) * K + ke);
    short8 a0 = *(const short8*)(x + (size_t)jl * K + ke);
    short8 a1 = *(const short8*)(x + (size_t)(16 + jl) * K + ke);
    acc0 = __builtin_amdgcn_mfma_f32_16x16x32_bf16(a0, bw, acc0, 0, 0, 0);
    acc1 = __builtin_amdgcn_mfma_f32_16x16x32_bf16(a1, bw, acc1, 0, 0, 0);
  }
#pragma unroll
  for (int r = 0; r < 4; ++r) {
    red[wid][kg * 4 + r][jl] = acc0[r];
    red[wid][16 + kg * 4 + r][jl] = acc1[r];
  }
  __syncthreads();
  const int tid = threadIdx.x;
#pragma unroll
  for (int u = 0; u < 2; ++u) {
    int oi = tid * 2 + u;
    int m = oi >> 4, j = oi & 15;
    float v = red[0][m][j] + red[1][m][j] + red[2][m][j] + red[3][m][j];
    int jg = jb + j;
    out[(size_t)m * obstride + jg] = v + bias[jg];
  }
}

// --------------------------- fused gate GEMM + LSTM cell (bf16 W, all 4 gates)
// block kb computes k-columns [kb*16, kb*16+16) for gates i,f,g,o, then the cell.
__global__ __launch_bounds__(256) void k_gates_cell(
    const unsigned short* __restrict__ x1, int K1,
    const unsigned short* __restrict__ x2, int K2,
    const unsigned short* __restrict__ W1, const unsigned short* __restrict__ W2,
    const float* __restrict__ bih, const float* __restrict__ bhh,
    float* __restrict__ cl, float* __restrict__ hl, unsigned short* __restrict__ hbf) {
  __shared__ float red[4][4][32][16];  // [wave][gate][m][j] = 32 KB
  const int lane = threadIdx.x & 63, wid = threadIdx.x >> 6;
  const int jb = blockIdx.x * 16, jl = lane & 15, kg = lane >> 4;
  f32x4 acc[4][2];
#pragma unroll
  for (int g = 0; g < 4; ++g) { acc[g][0] = 0.f; acc[g][1] = 0.f; }
  const int s1 = K1 >> 5;
  const int per = (s1 + (K2 >> 5)) >> 2;
  const int send = (wid + 1) * per;
  for (int s = wid * per; s < send; ++s) {
    const unsigned short* x; const unsigned short* W; int K, k0;
    if (s < s1) { x = x1; W = W1; K = K1; k0 = s * 32; }
    else       { x = x2; W = W2; K = K2; k0 = (s - s1) * 32; }
    const int ke = k0 + kg * 8;
    short8 a0 = *(const short8*)(x + (size_t)jl * K + ke);
    short8 a1 = *(const short8*)(x + (size_t)(16 + jl) * K + ke);
#pragma unroll
    for (int g = 0; g < 4; ++g) {
      short8 bw = *(const short8*)(W + (size_t)(g * H + jb + jl) * K + ke);
      acc[g][0] = __builtin_amdgcn_mfma_f32_16x16x32_bf16(a0, bw, acc[g][0], 0, 0, 0);
      acc[g][1] = __builtin_amdgcn_mfma_f32_16x16x32_bf16(a1, bw, acc[g][1], 0, 0, 0);
    }
  }
#pragma unroll
  for (int g = 0; g < 4; ++g)
#pragma unroll
    for (int r = 0; r < 4; ++r) {
      red[wid][g][kg * 4 + r][jl] = acc[g][0][r];
      red[wid][g][16 + kg * 4 + r][jl] = acc[g][1][r];
    }
  __syncthreads();
  const int tid = threadIdx.x;
#pragma unroll
  for (int u = 0; u < 2; ++u) {
    int oi = tid * 2 + u;       // 0..511
    int m = oi >> 4, j = oi & 15;
    int kglob = jb + j;
    float gate[4];
#pragma unroll
    for (int g = 0; g < 4; ++g)
      gate[g] = red[0][g][m][j] + red[1][g][m][j] + red[2][g][m][j] + red[3][g][m][j]
              + bih[g * H + kglob] + bhh[g * H + kglob];
    int idx = m * H + kglob;
    float cn = sigmoidf_(gate[1]) * cl[idx] + sigmoidf_(gate[0]) * tanhf(gate[2]);
    float hn = sigmoidf_(gate[3]) * tanhf(cn);
    cl[idx] = cn;
    hl[idx] = hn;
    hbf[idx] = bf16u(hn);
  }
}

// ------------------------------------------- LN of h[2] row -> olbf (bf16)
__global__ void k_ln(const float* __restrict__ hrow, const float* __restrict__ g,
                     const float* __restrict__ bta, unsigned short* __restrict__ olbf) {
  __shared__ float rbuf[4];
  int b = blockIdx.x, tid = threadIdx.x;
  float hv[4];
#pragma unroll
  for (int r = 0; r < 4; ++r) hv[r] = hrow[b * H + r * 256 + tid];
  float m = blk_sum256(hv[0] + hv[1] + hv[2] + hv[3], rbuf) * (1.f / H);
  float vs = 0.f;
#pragma unroll
  for (int r = 0; r < 4; ++r) { float d = hv[r] - m; vs += d * d; }
  float var = blk_sum256(vs, rbuf) * (1.f / H);
  float rstd = rsqrtf(var + 1e-5f);
#pragma unroll
  for (int r = 0; r < 4; ++r) {
    int k = r * 256 + tid;
    olbf[b * H + k] = bf16u((hv[r] - m) * rstd * g[k] + bta[k]);
  }
}

// ================= fallback (round-3) kernels: f32 W converted in-register ==
__global__ __launch_bounds__(256) void k_mfma_skinny(
    const unsigned short* __restrict__ x1, const float* __restrict__ W1, int K1,
    const unsigned short* __restrict__ x2, const float* __restrict__ W2, int K2,
    const float* __restrict__ b1, const float* __restrict__ b2,
    float* __restrict__ out, int obstride) {
  __shared__ float red[4][32][16];
  const int lane = threadIdx.x & 63, wid = threadIdx.x >> 6;
  const int jb = blockIdx.x * 16;
  const int jl = lane & 15, kg = lane >> 4;
  f32x4 acc0 = {0.f, 0.f, 0.f, 0.f}, acc1 = {0.f, 0.f, 0.f, 0.f};
  const int s1 = K1 >> 5, s2 = K2 >> 5;
  const int per = (s1 + s2) >> 2;
  const int send = (wid + 1) * per;
  for (int s = wid * per; s < send; ++s) {
    const unsigned short* x; const float* W; int K, k0;
    if (s < s1) { x = x1; W = W1; K = K1; k0 = s * 32; }
    else       { x = x2; W = W2; K = K2; k0 = (s - s1) * 32; }
    const int ke = k0 + kg * 8;
    const float* wp = W + (size_t)(jb + jl) * K + ke;
    f32x4 w0 = *(const f32x4*)wp;
    f32x4 w1 = *(const f32x4*)(wp + 4);
    short8 bw;
    bw[0] = (short)bf16u(w0[0]); bw[1] = (short)bf16u(w0[1]);
    bw[2] = (short)bf16u(w0[2]); bw[3] = (short)bf16u(w0[3]);
    bw[4] = (short)bf16u(w1[0]); bw[5] = (short)bf16u(w1[1]);
    bw[6] = (short)bf16u(w1[2]); bw[7] = (short)bf16u(w1[3]);
    short8 a0 = *(const short8*)(x + (size_t)jl * K + ke);
    short8 a1 = *(const short8*)(x + (size_t)(16 + jl) * K + ke);
    acc0 = __builtin_amdgcn_mfma_f32_16x16x32_bf16(a0, bw, acc0, 0, 0, 0);
    acc1 = __builtin_amdgcn_mfma_f32_16x16x32_bf16(a1, bw, acc1, 0, 0, 0);
  }
#pragma unroll
  for (int r = 0; r < 4; ++r) {
    red[wid][kg * 4 + r][jl] = acc0[r];
    red[wid][16 + kg * 4 + r][jl] = acc1[r];
  }
  __syncthreads();
  const int tid = threadIdx.x;
#pragma unroll
  for (int u = 0; u < 2; ++u) {
    int oi = tid * 2 + u;
    int m = oi >> 4, j = oi & 15;
    float v = red[0][m][j] + red[1][m][j] + red[2][m][j] + red[3][m][j];
    int jg = jb + j;
    v += (b1 ? b1[jg] : 0.f) + (b2 ? b2[jg] : 0.f);
    out[(size_t)m * obstride + jg] = v;
  }
}

__global__ void k_cell(const float* __restrict__ gat, float* __restrict__ cl,
                       float* __restrict__ hl, unsigned short* __restrict__ hbf) {
  int idx = blockIdx.x * 256 + threadIdx.x;
  int b = idx >> 10, k = idx & 1023;
  const float* gb = gat + (size_t)b * H4;
  float i_ = gb[k], f_ = gb[H + k], g_ = gb[2 * H + k], o_ = gb[3 * H + k];
  float cn = sigmoidf_(f_) * cl[idx] + sigmoidf_(i_) * tanhf(g_);
  float hn = sigmoidf_(o_) * tanhf(cn);
  cl[idx] = cn;
  hl[idx] = hn;
  hbf[idx] = bf16u(hn);
}

__global__ void k_cell2ln(const float* __restrict__ gat, float* __restrict__ cl,
                          float* __restrict__ hl, const float* __restrict__ g,
                          const float* __restrict__ bta, unsigned short* __restrict__ olbf,
                          unsigned short* __restrict__ hbf) {
  __shared__ float rbuf[4];
  int b = blockIdx.x, tid = threadIdx.x;
  const float* gb = gat + (size_t)b * H4;
  float hv[4];
#pragma unroll
  for (int r = 0; r < 4; ++r) {
    int k = r * 256 + tid;
    float i_ = gb[k], f_ = gb[H + k], g_ = gb[2 * H + k], o_ = gb[3 * H + k];
    float cn = sigmoidf_(f_) * cl[b * H + k] + sigmoidf_(i_) * tanhf(g_);
    float hn = sigmoidf_(o_) * tanhf(cn);
    cl[b * H + k] = cn;
    hl[b * H + k] = hn;
    hbf[b * H + k] = bf16u(hn);
    hv[r] = hn;
  }
  float m = blk_sum256(hv[0] + hv[1] + hv[2] + hv[3], rbuf) * (1.f / H);
  float vs = 0.f;
#pragma unroll
  for (int r = 0; r < 4; ++r) { float d = hv[r] - m; vs += d * d; }
  float var = blk_sum256(vs, rbuf) * (1.f / H);
  float rstd = rsqrtf(var + 1e-5f);
#pragma unroll
  for (int r = 0; r < 4; ++r) {
    int k = r * 256 + tid;
    olbf[b * H + k] = bf16u((hv[r] - m) * rstd * g[k] + bta[k]);
  }
}

// ---------------------------------------------------------------------------
extern "C" void kernel_launch(void* const* d_in, const int* in_sizes, int n_in,
                              void* d_out, int out_size, void* d_ws, size_t ws_size,
                              hipStream_t stream) {
  (void)in_sizes; (void)n_in; (void)out_size;
  const float* enc = (const float*)d_in[0];
  const float* h0 = (const float*)d_in[1];
  const float* c0 = (const float*)d_in[2];
  const int* vlen = (const int*)d_in[3];
  const int* target = (const int*)d_in[4];
  const float* emb_table = (const float*)d_in[5];
  const float* Wa = (const float*)d_in[6];
  const float* ba = (const float*)d_in[7];
  const float* Ua = (const float*)d_in[8];
  const float* ub = (const float*)d_in[9];
  const float* Va = (const float*)d_in[10];
  const float* vb = (const float*)d_in[11];
  const float* temp = (const float*)d_in[12];
  const float* Wih[3] = {(const float*)d_in[13], (const float*)d_in[17], (const float*)d_in[21]};
  const float* Whh[3] = {(const float*)d_in[14], (const float*)d_in[18], (const float*)d_in[22]};
  const float* bih[3] = {(const float*)d_in[15], (const float*)d_in[19], (const float*)d_in[23]};
  const float* bhh[3] = {(const float*)d_in[16], (const float*)d_in[20], (const float*)d_in[24]};
  const float* fcw = (const float*)d_in[25];
  const float* fcb = (const float*)d_in[26];
  const float* eng = (const float*)d_in[27];
  const float* enb = (const float*)d_in[28];
  const float* cng = (const float*)d_in[29];
  const float* cnb = (const float*)d_in[30];
  const float* ong = (const float*)d_in[31];
  const float* onb = (const float*)d_in[32];

  float* ws = (float*)d_ws;
  float* ukeys = ws + WS_UKEYS;
  float* embv = ws + WS_EMB;
  float* hst = ws + WS_H;
  float* cst = ws + WS_C;
  float* qwa = ws + WS_QWA;
  float* sco = ws + WS_SCO;
  float* gat = ws + WS_GAT;
  unsigned short* hbf = (unsigned short*)(ws + WS_HBF);
  unsigned short* xcbf = (unsigned short*)(ws + WS_XCBF);
  unsigned short* olbf = (unsigned short*)(ws + WS_OLBF);
  unsigned short* wbf = (unsigned short*)(ws + WS_WBF);
  float* out = (float*)d_out;

  const bool big = ws_size >= NEED_WS_BYTES;

  k_init<<<768, 256, 0, stream>>>(h0, c0, hst, cst, hbf);
  k_gemm_nt<<<dim3(H / 64, (B * S) / 128), 256, 0, stream>>>(enc, Ua, ub, ukeys, H, H);
  k_embln<<<T * B, 256, 0, stream>>>(emb_table, target, eng, enb, embv);

  if (big) {
    k_cvt<<<1024, 256, 0, stream>>>(Wa, wbf + OW_WA, H * H / 4);
    k_cvt<<<1024, 256, 0, stream>>>(Wih[0], wbf + OW_WIH0, H4 * H2 / 4);
    k_cvt<<<1024, 256, 0, stream>>>(Whh[0], wbf + OW_WHH0, H4 * H / 4);
    k_cvt<<<1024, 256, 0, stream>>>(Wih[1], wbf + OW_WIH1, H4 * H / 4);
    k_cvt<<<1024, 256, 0, stream>>>(Whh[1], wbf + OW_WHH1, H4 * H / 4);
    k_cvt<<<1024, 256, 0, stream>>>(Wih[2], wbf + OW_WIH2, H4 * H / 4);
    k_cvt<<<1024, 256, 0, stream>>>(Whh[2], wbf + OW_WHH2, H4 * H / 4);
    k_cvt<<<2048, 256, 0, stream>>>(fcw, wbf + OW_FCW, V * H / 4);

    for (int t = 0; t < T; ++t) {
      k_skinny_bf<<<H / 16, 256, 0, stream>>>(hbf + 2 * BH, wbf + OW_WA, H, ba, qwa, H);
      k_scores<<<(B * S) / 4, 256, 0, stream>>>(qwa, ukeys, Va, vb, temp, vlen, sco);
      k_smctx<<<B, 256, 0, stream>>>(sco, enc, embv + (size_t)t * BH, cng, cnb, xcbf,
                                     out + ATTN_OFF, t);
      k_gates_cell<<<H / 16, 256, 0, stream>>>(xcbf, H2, hbf, H,
                                               wbf + OW_WIH0, wbf + OW_WHH0,
                                               bih[0], bhh[0], cst, hst, hbf);
      k_gates_cell<<<H / 16, 256, 0, stream>>>(hbf, H, hbf + BH, H,
                                               wbf + OW_WIH1, wbf + OW_WHH1,
                                               bih[1], bhh[1], cst + BH, hst + BH, hbf + BH);
      k_gates_cell<<<H / 16, 256, 0, stream>>>(hbf + BH, H, hbf + 2 * BH, H,
                                               wbf + OW_WIH2, wbf + OW_WHH2,
                                               bih[2], bhh[2], cst + 2 * BH, hst + 2 * BH,
                                               hbf + 2 * BH);
      k_ln<<<B, 256, 0, stream>>>(hst + 2 * BH, ong, onb, olbf);
      k_skinny_bf<<<V / 16, 256, 0, stream>>>(olbf, wbf + OW_FCW, H, fcb,
                                              out + (size_t)t * V, T * V);
    }
  } else {
    // fallback: round-3 proven path (in-register weight conversion)
    for (int t = 0; t < T; ++t) {
      k_mfma_skinny<<<H / 16, 256, 0, stream>>>(hbf + 2 * BH, Wa, H, nullptr, nullptr, 0,
                                                ba, nullptr, qwa, H);
      k_scores<<<(B * S) / 4, 256, 0, stream>>>(qwa, ukeys, Va, vb, temp, vlen, sco);
      k_smctx<<<B, 256, 0, stream>>>(sco, enc, embv + (size_t)t * BH, cng, cnb, xcbf,
                                     out + ATTN_OFF, t);
      k_mfma_skinny<<<H4 / 16, 256, 0, stream>>>(xcbf, Wih[0], H2, hbf, Whh[0], H,
                                                 bih[0], bhh[0], gat, H4);
      k_cell<<<BH / 256, 256, 0, stream>>>(gat, cst, hst, hbf);
      k_mfma_skinny<<<H4 / 16, 256, 0, stream>>>(hbf, Wih[1], H, hbf + BH, Whh[1], H,
                                                 bih[1], bhh[1], gat, H4);
      k_cell<<<BH / 256, 256, 0, stream>>>(gat, cst + BH, hst + BH, hbf + BH);
      k_mfma_skinny<<<H4 / 16, 256, 0, stream>>>(hbf + BH, Wih[2], H, hbf + 2 * BH, Whh[2], H,
                                                 bih[2], bhh[2], gat, H4);
      k_cell2ln<<<B, 256, 0, stream>>>(gat, cst + 2 * BH, hst + 2 * BH, ong, onb, olbf,
                                       hbf + 2 * BH);
      k_mfma_skinny<<<V / 16, 256, 0, stream>>>(olbf, fcw, H, nullptr, nullptr, 0,
                                                fcb, nullptr, out + (size_t)t * V, T * V);
    }
  }
  k_fin<<<768, 256, 0, stream>>>(hst, cst, out);
}

// Round 5
// 3380.863 us; speedup vs baseline: 5.3485x; 1.7131x over previous
//
#include <hip/hip_runtime.h>
#include <math.h>

#define DEV_INLINE __device__ __forceinline__

constexpr int B = 32, S = 128, H = 1024, V = 32000, T = 50, L = 3;
constexpr int H2 = 2 * H, H4 = 4 * H;
constexpr int BH = B * H;

// ---- d_out layout (floats): logits (B,T,V) | hT (L,B,H) | cT (L,B,H) | attn (B,T,S)
constexpr size_t HT_OFF   = (size_t)B * T * V;
constexpr size_t CT_OFF   = HT_OFF + (size_t)L * B * H;
constexpr size_t ATTN_OFF = CT_OFF + (size_t)L * B * H;

// ---- workspace layout (float units; bf16 buffers consume half-slots)
constexpr size_t WS_UKEYS = 0;                                  // B*S*H f32
constexpr size_t WS_EMBBF = WS_UKEYS + (size_t)B * S * H;       // T*BH ushort
constexpr size_t WS_H2ALL = WS_EMBBF + (size_t)T * BH / 2;      // T*BH f32
constexpr size_t WS_H     = WS_H2ALL + (size_t)T * BH;          // L*BH f32
constexpr size_t WS_C     = WS_H + (size_t)L * BH;              // L*BH f32
constexpr size_t WS_QWA   = WS_C + (size_t)L * BH;              // BH f32
constexpr size_t WS_SCO   = WS_QWA + (size_t)BH;                // B*S f32
constexpr size_t WS_GAT   = WS_SCO + (size_t)B * S;             // B*H4 f32 (fallback)
constexpr size_t WS_HBF   = WS_GAT + (size_t)B * H4;            // 2 banks L*BH ushort
constexpr size_t WS_XCBF  = WS_HBF + (size_t)2 * L * BH / 2;    // B*H2 ushort
constexpr size_t WS_OLALL = WS_XCBF + (size_t)B * H2 / 2;       // T*BH ushort
constexpr size_t WS_WBF   = WS_OLALL + (size_t)T * BH / 2;      // = 7,966,720 f

// bf16 weight region offsets (ushort units from WS_WBF base)
constexpr size_t OW_WA   = 0;
constexpr size_t OW_WIH0 = OW_WA   + (size_t)H * H;
constexpr size_t OW_WHH0 = OW_WIH0 + (size_t)H4 * H2;
constexpr size_t OW_WIH1 = OW_WHH0 + (size_t)H4 * H;
constexpr size_t OW_WHH1 = OW_WIH1 + (size_t)H4 * H;
constexpr size_t OW_WIH2 = OW_WHH1 + (size_t)H4 * H;
constexpr size_t OW_WHH2 = OW_WIH2 + (size_t)H4 * H;
constexpr size_t OW_FCW  = OW_WHH2 + (size_t)H4 * H;
constexpr size_t OW_END  = OW_FCW  + (size_t)V * H;             // 63,176,704 ushort
constexpr size_t NEED_WS_BYTES = WS_WBF * 4 + OW_END * 2;       // 158,220,288

typedef __attribute__((ext_vector_type(8))) short short8;
typedef __attribute__((ext_vector_type(4))) float f32x4;
typedef __attribute__((ext_vector_type(4))) unsigned short u16x4;

DEV_INLINE float sigmoidf_(float x) { return 1.f / (1.f + expf(-x)); }

DEV_INLINE unsigned short bf16u(float f) {  // RNE f32->bf16 bits
  union { float f; unsigned u; } v; v.f = f;
  unsigned r = v.u + 0x7fffu + ((v.u >> 16) & 1u);
  return (unsigned short)(r >> 16);
}

DEV_INLINE float wave_sum(float v) {
#pragma unroll
  for (int o = 32; o; o >>= 1) v += __shfl_xor(v, o, 64);
  return v;
}

DEV_INLINE float blk_sum256(float v, float* buf) {
  v = wave_sum(v);
  __syncthreads();
  if ((threadIdx.x & 63) == 0) buf[threadIdx.x >> 6] = v;
  __syncthreads();
  return buf[0] + buf[1] + buf[2] + buf[3];
}

// ---------------------------------------------------------------- state copies
__global__ void k_init(const float* __restrict__ h0, const float* __restrict__ c0,
                       float* __restrict__ hst, float* __restrict__ cst,
                       unsigned short* __restrict__ hbf) {
  int idx = blockIdx.x * 256 + threadIdx.x;
  if (idx < L * BH) { hst[idx] = h0[idx]; hbf[idx] = bf16u(h0[idx]); }
  else cst[idx - L * BH] = c0[idx - L * BH];
}

// h0,h1 from hst; h2 from h2src; c from cst
__global__ void k_fin(const float* __restrict__ hst, const float* __restrict__ h2src,
                      const float* __restrict__ cst, float* __restrict__ out) {
  int idx = blockIdx.x * 256 + threadIdx.x;  // 0 .. 2*L*BH-1
  if (idx < 2 * BH) out[HT_OFF + idx] = hst[idx];
  else if (idx < 3 * BH) out[HT_OFF + idx] = h2src[idx - 2 * BH];
  else out[HT_OFF + idx] = cst[idx - 3 * BH];
}

// ---------------------------------------------- f32 -> bf16 weight conversion
__global__ void k_cvt(const float* __restrict__ src, unsigned short* __restrict__ dst,
                      int n4) {
  int i = blockIdx.x * 256 + threadIdx.x;
  int stride = gridDim.x * 256;
  for (; i < n4; i += stride) {
    f32x4 v = *(const f32x4*)(src + (size_t)i * 4);
    u16x4 o;
    o[0] = bf16u(v[0]); o[1] = bf16u(v[1]); o[2] = bf16u(v[2]); o[3] = bf16u(v[3]);
    *(u16x4*)(dst + (size_t)i * 4) = o;
  }
}

// ------------------------------------------------- Ukeys = enc @ Ua^T + ub (f32, one-time)
__global__ __launch_bounds__(256) void k_gemm_nt(
    const float* __restrict__ A, const float* __restrict__ Bw,
    const float* __restrict__ bias, float* __restrict__ C, int N, int K) {
  __shared__ float As[16][132];
  __shared__ float Bs[16][68];
  const int i0 = blockIdx.y * 128, j0 = blockIdx.x * 64;
  const int ty = threadIdx.x >> 4, tx = threadIdx.x & 15;
  float acc[8][4] = {};
  for (int k0 = 0; k0 < K; k0 += 16) {
#pragma unroll
    for (int r = 0; r < 8; ++r) {
      int i = threadIdx.x + 256 * r;
      int mm = i >> 4, kk = i & 15;
      As[kk][mm] = A[(size_t)(i0 + mm) * K + k0 + kk];
    }
#pragma unroll
    for (int r = 0; r < 4; ++r) {
      int i = threadIdx.x + 256 * r;
      int nn = i >> 4, kk = i & 15;
      Bs[kk][nn] = Bw[(size_t)(j0 + nn) * K + k0 + kk];
    }
    __syncthreads();
#pragma unroll
    for (int kk = 0; kk < 16; ++kk) {
      float a[8], bb[4];
#pragma unroll
      for (int i = 0; i < 8; ++i) a[i] = As[kk][ty * 8 + i];
#pragma unroll
      for (int j = 0; j < 4; ++j) bb[j] = Bs[kk][tx * 4 + j];
#pragma unroll
      for (int i = 0; i < 8; ++i)
#pragma unroll
        for (int j = 0; j < 4; ++j) acc[i][j] = fmaf(a[i], bb[j], acc[i][j]);
    }
    __syncthreads();
  }
#pragma unroll
  for (int i = 0; i < 8; ++i) {
    size_t row = (size_t)(i0 + ty * 8 + i) * N;
#pragma unroll
    for (int j = 0; j < 4; ++j) {
      int col = j0 + tx * 4 + j;
      C[row + col] = acc[i][j] + bias[col];
    }
  }
}

// --------------------------------------- emb_all[t,b,:] = LN(embedding[tok]) -> bf16
__global__ void k_embln(const float* __restrict__ table, const int* __restrict__ target,
                        const float* __restrict__ g, const float* __restrict__ bta,
                        unsigned short* __restrict__ out) {
  __shared__ float rbuf[4];
  int idx = blockIdx.x;  // t*B + b
  int t = idx >> 5, b = idx & 31;
  int tok = (t == 0) ? 0 : target[b * T + (t - 1)];
  const float* e = table + (size_t)tok * H;
  int tid = threadIdx.x;
  float x[4];
#pragma unroll
  for (int r = 0; r < 4; ++r) x[r] = e[r * 256 + tid];
  float m = blk_sum256(x[0] + x[1] + x[2] + x[3], rbuf) * (1.f / H);
  float vs = 0.f;
#pragma unroll
  for (int r = 0; r < 4; ++r) { float d = x[r] - m; vs += d * d; }
  float var = blk_sum256(vs, rbuf) * (1.f / H);
  float rstd = rsqrtf(var + 1e-5f);
  unsigned short* o = out + (size_t)idx * H;
#pragma unroll
  for (int r = 0; r < 4; ++r) {
    int h = r * 256 + tid;
    o[h] = bf16u((x[r] - m) * rstd * g[h] + bta[h]);
  }
}

// ------------------------------------------------------- attention scores
__global__ void k_scores(const float* __restrict__ qwa, const float* __restrict__ ukeys,
                         const float* __restrict__ va, const float* __restrict__ vb,
                         const float* __restrict__ temp, const int* __restrict__ vlen,
                         float* __restrict__ sco) {
  int lane = threadIdx.x & 63, wid = threadIdx.x >> 6;
  int idx = blockIdx.x * 4 + wid;  // b*S + s
  int b = idx >> 7, s = idx & 127;
  const float* uk = ukeys + (size_t)idx * H;
  const float* q = qwa + (size_t)b * H;
  float a = 0.f;
#pragma unroll
  for (int i = 0; i < 16; ++i) {
    int k = i * 64 + lane;
    a = fmaf(va[k], tanhf(q[k] + uk[k]), a);
  }
  a = wave_sum(a);
  if (lane == 0) {
    float val = (a + vb[0]) / temp[0];
    if (s >= vlen[b]) val = -1e9f;
    sco[idx] = val;
  }
}

// ------ softmax + attn write + ctx + LN + build xcat_bf16 = [emb | ctxn]
__global__ void k_smctx(const float* __restrict__ sco, const float* __restrict__ enc,
                        const unsigned short* __restrict__ embt, const float* __restrict__ g,
                        const float* __restrict__ bta, unsigned short* __restrict__ xbf,
                        float* __restrict__ attn, int t) {
  __shared__ float sw[S];
  __shared__ float rbuf[4];
  int b = blockIdx.x, tid = threadIdx.x;
  if (tid < 64) {
    float v0 = sco[b * S + tid], v1 = sco[b * S + 64 + tid];
    float m = fmaxf(v0, v1);
#pragma unroll
    for (int o = 32; o; o >>= 1) m = fmaxf(m, __shfl_xor(m, o, 64));
    float e0 = expf(v0 - m), e1 = expf(v1 - m);
    float ssum = wave_sum(e0 + e1);
    float inv = 1.f / ssum;
    sw[tid] = e0 * inv;
    sw[64 + tid] = e1 * inv;
  }
  __syncthreads();
  if (tid < S) attn[((size_t)b * T + t) * S + tid] = sw[tid];
  float v[4] = {0.f, 0.f, 0.f, 0.f};
  for (int s2 = 0; s2 < S; ++s2) {
    float wv = sw[s2];
    const float* er = enc + ((size_t)b * S + s2) * H;
#pragma unroll
    for (int r = 0; r < 4; ++r) v[r] = fmaf(wv, er[r * 256 + tid], v[r]);
  }
  float m = blk_sum256(v[0] + v[1] + v[2] + v[3], rbuf) * (1.f / H);
  float vs = 0.f;
#pragma unroll
  for (int r = 0; r < 4; ++r) { float d = v[r] - m; vs += d * d; }
  float var = blk_sum256(vs, rbuf) * (1.f / H);
  float rstd = rsqrtf(var + 1e-5f);
  unsigned short* xr = xbf + (size_t)b * H2;
#pragma unroll
  for (int r = 0; r < 4; ++r) {
    int h = r * 256 + tid;
    xr[H + h] = bf16u((v[r] - m) * rstd * g[h] + bta[h]);
    xr[h] = embt[(size_t)b * H + h];
  }
}

// ----------------------------------------------------- MFMA skinny GEMM (bf16 W)
// used for qWa. out[m,j] = sum_k x[m,k]*Wb[j,k] + bias[j]. 16 j/block, 4 waves split K.
__global__ __launch_bounds__(256) void k_skinny_bf(
    const unsigned short* __restrict__ x, const unsigned short* __restrict__ Wb, int K,
    const float* __restrict__ bias, float* __restrict__ out, int obstride) {
  __shared__ float red[4][32][16];
  const int lane = threadIdx.x & 63, wid = threadIdx.x >> 6;
  const int jb = blockIdx.x * 16;
  const int jl = lane & 15, kg = lane >> 4;
  f32x4 acc0 = {0.f, 0.f, 0.f, 0.f}, acc1 = {0.f, 0.f, 0.f, 0.f};
  const int per = (K >> 5) >> 2;
  const int send = (wid + 1) * per;
  for (int s = wid * per; s < send; ++s) {
    const int ke = s * 32 + kg * 8;
    short8 bw = *(const short8*)(Wb + (size_t)(jb + jl) * K + ke);
    short8 a0 = *(const short8*)(x + (size_t)jl * K + ke);
    short8 a1 = *(const short8*)(x + (size_t)(16 + jl) * K + ke);
    acc0 = __builtin_amdgcn_mfma_f32_16x16x32_bf16(a0, bw, acc0, 0, 0, 0);
    acc1 = __builtin_amdgcn_mfma_f32_16x16x32_bf16(a1, bw, acc1, 0, 0, 0);
  }
#pragma unroll
  for (int r = 0; r < 4; ++r) {
    red[wid][kg * 4 + r][jl] = acc0[r];
    red[wid][16 + kg * 4 + r][jl] = acc1[r];
  }
  __syncthreads();
  const int tid = threadIdx.x;
#pragma unroll
  for (int u = 0; u < 2; ++u) {
    int oi = tid * 2 + u;
    int m = oi >> 4, j = oi & 15;
    float v = red[0][m][j] + red[1][m][j] + red[2][m][j] + red[3][m][j];
    int jg = jb + j;
    out[(size_t)m * obstride + jg] = v + bias[jg];
  }
}

// ---------- fused gate GEMM + LSTM cell, j-tile 4, all gates packed (256 blocks)
// B-frag row fr = g*4+jj -> weight row g*H + jb + jj. Race-free: reads x2 from
// the READ hbf bank, writes the WRITE bank.
__global__ __launch_bounds__(256) void k_gates4(
    const unsigned short* __restrict__ x1, int K1,
    const unsigned short* __restrict__ x2, int K2,
    const unsigned short* __restrict__ W1, const unsigned short* __restrict__ W2,
    const float* __restrict__ bih, const float* __restrict__ bhh,
    float* __restrict__ cl, float* __restrict__ hl, unsigned short* __restrict__ hbfw) {
  __shared__ float red[4][32][17];
  const int lane = threadIdx.x & 63, wid = threadIdx.x >> 6;
  const int jb = blockIdx.x * 4;
  const int fr = lane & 15, kg = lane >> 4;
  const int wrow = (fr >> 2) * H + jb + (fr & 3);
  f32x4 acc0 = {0.f, 0.f, 0.f, 0.f}, acc1 = {0.f, 0.f, 0.f, 0.f};
  const int s1 = K1 >> 5, s2 = K2 >> 5;
  const int per = (s1 + s2) >> 2;
  const int sbeg = wid * per, send = sbeg + per;
  const int e1 = send < s1 ? send : s1;
#pragma unroll 4
  for (int s = sbeg; s < e1; ++s) {
    const int ke = s * 32 + kg * 8;
    short8 bw = *(const short8*)(W1 + (size_t)wrow * K1 + ke);
    short8 a0 = *(const short8*)(x1 + (size_t)fr * K1 + ke);
    short8 a1 = *(const short8*)(x1 + (size_t)(16 + fr) * K1 + ke);
    acc0 = __builtin_amdgcn_mfma_f32_16x16x32_bf16(a0, bw, acc0, 0, 0, 0);
    acc1 = __builtin_amdgcn_mfma_f32_16x16x32_bf16(a1, bw, acc1, 0, 0, 0);
  }
  const int b2 = sbeg > s1 ? sbeg : s1;
#pragma unroll 4
  for (int s = b2; s < send; ++s) {
    const int ke = (s - s1) * 32 + kg * 8;
    short8 bw = *(const short8*)(W2 + (size_t)wrow * K2 + ke);
    short8 a0 = *(const short8*)(x2 + (size_t)fr * K2 + ke);
    short8 a1 = *(const short8*)(x2 + (size_t)(16 + fr) * K2 + ke);
    acc0 = __builtin_amdgcn_mfma_f32_16x16x32_bf16(a0, bw, acc0, 0, 0, 0);
    acc1 = __builtin_amdgcn_mfma_f32_16x16x32_bf16(a1, bw, acc1, 0, 0, 0);
  }
#pragma unroll
  for (int r = 0; r < 4; ++r) {
    red[wid][kg * 4 + r][fr] = acc0[r];
    red[wid][16 + kg * 4 + r][fr] = acc1[r];
  }
  __syncthreads();
  const int tid = threadIdx.x;
  if (tid < 128) {
    int m = tid >> 2, jj = tid & 3, kcol = jb + jj;
    float gate[4];
#pragma unroll
    for (int g = 0; g < 4; ++g) {
      int f = g * 4 + jj;
      gate[g] = red[0][m][f] + red[1][m][f] + red[2][m][f] + red[3][m][f]
              + bih[g * H + kcol] + bhh[g * H + kcol];
    }
    int idx = m * H + kcol;
    float cn = sigmoidf_(gate[1]) * cl[idx] + sigmoidf_(gate[0]) * tanhf(gate[2]);
    float hn = sigmoidf_(gate[3]) * tanhf(cn);
    cl[idx] = cn;
    hl[idx] = hn;
    hbfw[idx] = bf16u(hn);
  }
}

// ------------------------------- batch LN of all h2 rows -> olbf_all (bf16)
__global__ void k_ln_all(const float* __restrict__ h2all, const float* __restrict__ g,
                         const float* __restrict__ bta, unsigned short* __restrict__ olbf) {
  __shared__ float rbuf[4];
  int row = blockIdx.x, tid = threadIdx.x;  // row = t*B + b
  const float* hr = h2all + (size_t)row * H;
  float hv[4];
#pragma unroll
  for (int r = 0; r < 4; ++r) hv[r] = hr[r * 256 + tid];
  float m = blk_sum256(hv[0] + hv[1] + hv[2] + hv[3], rbuf) * (1.f / H);
  float vs = 0.f;
#pragma unroll
  for (int r = 0; r < 4; ++r) { float d = hv[r] - m; vs += d * d; }
  float var = blk_sum256(vs, rbuf) * (1.f / H);
  float rstd = rsqrtf(var + 1e-5f);
  unsigned short* o = olbf + (size_t)row * H;
#pragma unroll
  for (int r = 0; r < 4; ++r) {
    int k = r * 256 + tid;
    o[k] = bf16u((hv[r] - m) * rstd * g[k] + bta[k]);
  }
}

// -------------------- batched logits GEMM: X[1600x1024] @ Wb[32000x1024]^T
// tile 64(M) x 128(N) x 64(K); 4 waves in 2x2; wave tile 32x64.
__global__ __launch_bounds__(256) void k_gemm_logits(
    const unsigned short* __restrict__ X, const unsigned short* __restrict__ Wb,
    const float* __restrict__ bias, float* __restrict__ out) {
  __shared__ unsigned short As[64][72];
  __shared__ unsigned short Bs[128][72];
  const int tid = threadIdx.x, lane = tid & 63, wid = tid >> 6;
  const int wm = wid >> 1, wn = wid & 1;
  const int n0 = blockIdx.x * 128, m0 = blockIdx.y * 64;
  const int fr = lane & 15, kg = lane >> 4;
  f32x4 acc[2][4];
#pragma unroll
  for (int i = 0; i < 2; ++i)
#pragma unroll
    for (int j = 0; j < 4; ++j) acc[i][j] = {0.f, 0.f, 0.f, 0.f};
  for (int k0 = 0; k0 < H; k0 += 64) {
    __syncthreads();
#pragma unroll
    for (int r = 0; r < 2; ++r) {
      int i = tid + 256 * r, row = i >> 3, c8 = (i & 7) * 8;
      *(short8*)&As[row][c8] = *(const short8*)(X + (size_t)(m0 + row) * H + k0 + c8);
    }
#pragma unroll
    for (int r = 0; r < 4; ++r) {
      int i = tid + 256 * r, row = i >> 3, c8 = (i & 7) * 8;
      *(short8*)&Bs[row][c8] = *(const short8*)(Wb + (size_t)(n0 + row) * H + k0 + c8);
    }
    __syncthreads();
#pragma unroll
    for (int kk = 0; kk < 64; kk += 32) {
      short8 av[2], bv[4];
      av[0] = *(const short8*)&As[wm * 32 + fr][kk + kg * 8];
      av[1] = *(const short8*)&As[wm * 32 + 16 + fr][kk + kg * 8];
#pragma unroll
      for (int fn = 0; fn < 4; ++fn)
        bv[fn] = *(const short8*)&Bs[wn * 64 + fn * 16 + fr][kk + kg * 8];
#pragma unroll
      for (int fm = 0; fm < 2; ++fm)
#pragma unroll
        for (int fn = 0; fn < 4; ++fn)
          acc[fm][fn] = __builtin_amdgcn_mfma_f32_16x16x32_bf16(av[fm], bv[fn],
                                                                acc[fm][fn], 0, 0, 0);
    }
  }
#pragma unroll
  for (int fm = 0; fm < 2; ++fm)
#pragma unroll
    for (int fn = 0; fn < 4; ++fn)
#pragma unroll
      for (int r = 0; r < 4; ++r) {
        int m = m0 + wm * 32 + fm * 16 + kg * 4 + r;  // = t*B + b
        int n = n0 + wn * 64 + fn * 16 + fr;
        int b = m & 31, t = m >> 5;
        out[((size_t)b * T + t) * V + n] = acc[fm][fn][r] + bias[n];
      }
}

// ================= fallback (round-3) kernels: f32 W converted in-register ==
__global__ __launch_bounds__(256) void k_mfma_skinny(
    const unsigned short* __restrict__ x1, const float* __restrict__ W1, int K1,
    const unsigned short* __restrict__ x2, const float* __restrict__ W2, int K2,
    const float* __restrict__ b1, const float* __restrict__ b2,
    float* __restrict__ out, int obstride) {
  __shared__ float red[4][32][16];
  const int lane = threadIdx.x & 63, wid = threadIdx.x >> 6;
  const int jb = blockIdx.x * 16;
  const int jl = lane & 15, kg = lane >> 4;
  f32x4 acc0 = {0.f, 0.f, 0.f, 0.f}, acc1 = {0.f, 0.f, 0.f, 0.f};
  const int s1 = K1 >> 5, s2 = K2 >> 5;
  const int per = (s1 + s2) >> 2;
  const int send = (wid + 1) * per;
  for (int s = wid * per; s < send; ++s) {
    const unsigned short* x; const float* W; int K, k0;
    if (s < s1) { x = x1; W = W1; K = K1; k0 = s * 32; }
    else       { x = x2; W = W2; K = K2; k0 = (s - s1) * 32; }
    const int ke = k0 + kg * 8;
    const float* wp = W + (size_t)(jb + jl) * K + ke;
    f32x4 w0 = *(const f32x4*)wp;
    f32x4 w1 = *(const f32x4*)(wp + 4);
    short8 bw;
    bw[0] = (short)bf16u(w0[0]); bw[1] = (short)bf16u(w0[1]);
    bw[2] = (short)bf16u(w0[2]); bw[3] = (short)bf16u(w0[3]);
    bw[4] = (short)bf16u(w1[0]); bw[5] = (short)bf16u(w1[1]);
    bw[6] = (short)bf16u(w1[2]); bw[7] = (short)bf16u(w1[3]);
    short8 a0 = *(const short8*)(x + (size_t)jl * K + ke);
    short8 a1 = *(const short8*)(x + (size_t)(16 + jl) * K + ke);
    acc0 = __builtin_amdgcn_mfma_f32_16x16x32_bf16(a0, bw, acc0, 0, 0, 0);
    acc1 = __builtin_amdgcn_mfma_f32_16x16x32_bf16(a1, bw, acc1, 0, 0, 0);
  }
#pragma unroll
  for (int r = 0; r < 4; ++r) {
    red[wid][kg * 4 + r][jl] = acc0[r];
    red[wid][16 + kg * 4 + r][jl] = acc1[r];
  }
  __syncthreads();
  const int tid = threadIdx.x;
#pragma unroll
  for (int u = 0; u < 2; ++u) {
    int oi = tid * 2 + u;
    int m = oi >> 4, j = oi & 15;
    float v = red[0][m][j] + red[1][m][j] + red[2][m][j] + red[3][m][j];
    int jg = jb + j;
    v += (b1 ? b1[jg] : 0.f) + (b2 ? b2[jg] : 0.f);
    out[(size_t)m * obstride + jg] = v;
  }
}

__global__ void k_cell(const float* __restrict__ gat, float* __restrict__ cl,
                       float* __restrict__ hl, unsigned short* __restrict__ hbf) {
  int idx = blockIdx.x * 256 + threadIdx.x;
  int b = idx >> 10, k = idx & 1023;
  const float* gb = gat + (size_t)b * H4;
  float i_ = gb[k], f_ = gb[H + k], g_ = gb[2 * H + k], o_ = gb[3 * H + k];
  float cn = sigmoidf_(f_) * cl[idx] + sigmoidf_(i_) * tanhf(g_);
  float hn = sigmoidf_(o_) * tanhf(cn);
  cl[idx] = cn;
  hl[idx] = hn;
  hbf[idx] = bf16u(hn);
}

__global__ void k_cell2ln(const float* __restrict__ gat, float* __restrict__ cl,
                          float* __restrict__ hl, const float* __restrict__ g,
                          const float* __restrict__ bta, unsigned short* __restrict__ olbf,
                          unsigned short* __restrict__ hbf) {
  __shared__ float rbuf[4];
  int b = blockIdx.x, tid = threadIdx.x;
  const float* gb = gat + (size_t)b * H4;
  float hv[4];
#pragma unroll
  for (int r = 0; r < 4; ++r) {
    int k = r * 256 + tid;
    float i_ = gb[k], f_ = gb[H + k], g_ = gb[2 * H + k], o_ = gb[3 * H + k];
    float cn = sigmoidf_(f_) * cl[b * H + k] + sigmoidf_(i_) * tanhf(g_);
    float hn = sigmoidf_(o_) * tanhf(cn);
    cl[b * H + k] = cn;
    hl[b * H + k] = hn;
    hbf[b * H + k] = bf16u(hn);
    hv[r] = hn;
  }
  float m = blk_sum256(hv[0] + hv[1] + hv[2] + hv[3], rbuf) * (1.f / H);
  float vs = 0.f;
#pragma unroll
  for (int r = 0; r < 4; ++r) { float d = hv[r] - m; vs += d * d; }
  float var = blk_sum256(vs, rbuf) * (1.f / H);
  float rstd = rsqrtf(var + 1e-5f);
#pragma unroll
  for (int r = 0; r < 4; ++r) {
    int k = r * 256 + tid;
    olbf[b * H + k] = bf16u((hv[r] - m) * rstd * g[k] + bta[k]);
  }
}

// ---------------------------------------------------------------------------
extern "C" void kernel_launch(void* const* d_in, const int* in_sizes, int n_in,
                              void* d_out, int out_size, void* d_ws, size_t ws_size,
                              hipStream_t stream) {
  (void)in_sizes; (void)n_in; (void)out_size;
  const float* enc = (const float*)d_in[0];
  const float* h0 = (const float*)d_in[1];
  const float* c0 = (const float*)d_in[2];
  const int* vlen = (const int*)d_in[3];
  const int* target = (const int*)d_in[4];
  const float* emb_table = (const float*)d_in[5];
  const float* Wa = (const float*)d_in[6];
  const float* ba = (const float*)d_in[7];
  const float* Ua = (const float*)d_in[8];
  const float* ub = (const float*)d_in[9];
  const float* Va = (const float*)d_in[10];
  const float* vb = (const float*)d_in[11];
  const float* temp = (const float*)d_in[12];
  const float* Wih[3] = {(const float*)d_in[13], (const float*)d_in[17], (const float*)d_in[21]};
  const float* Whh[3] = {(const float*)d_in[14], (const float*)d_in[18], (const float*)d_in[22]};
  const float* bih[3] = {(const float*)d_in[15], (const float*)d_in[19], (const float*)d_in[23]};
  const float* bhh[3] = {(const float*)d_in[16], (const float*)d_in[20], (const float*)d_in[24]};
  const float* fcw = (const float*)d_in[25];
  const float* fcb = (const float*)d_in[26];
  const float* eng = (const float*)d_in[27];
  const float* enb = (const float*)d_in[28];
  const float* cng = (const float*)d_in[29];
  const float* cnb = (const float*)d_in[30];
  const float* ong = (const float*)d_in[31];
  const float* onb = (const float*)d_in[32];

  float* ws = (float*)d_ws;
  float* ukeys = ws + WS_UKEYS;
  unsigned short* embbf = (unsigned short*)(ws + WS_EMBBF);
  float* h2all = ws + WS_H2ALL;
  float* hst = ws + WS_H;
  float* cst = ws + WS_C;
  float* qwa = ws + WS_QWA;
  float* sco = ws + WS_SCO;
  float* gat = ws + WS_GAT;
  unsigned short* hbf = (unsigned short*)(ws + WS_HBF);  // 2 banks of L*BH
  unsigned short* xcbf = (unsigned short*)(ws + WS_XCBF);
  unsigned short* olall = (unsigned short*)(ws + WS_OLALL);
  unsigned short* wbf = (unsigned short*)(ws + WS_WBF);
  float* out = (float*)d_out;

  const bool big = ws_size >= NEED_WS_BYTES;

  k_init<<<768, 256, 0, stream>>>(h0, c0, hst, cst, hbf);
  k_gemm_nt<<<dim3(H / 64, (B * S) / 128), 256, 0, stream>>>(enc, Ua, ub, ukeys, H, H);
  k_embln<<<T * B, 256, 0, stream>>>(emb_table, target, eng, enb, embbf);

  if (big) {
    k_cvt<<<1024, 256, 0, stream>>>(Wa, wbf + OW_WA, H * H / 4);
    k_cvt<<<1024, 256, 0, stream>>>(Wih[0], wbf + OW_WIH0, H4 * H2 / 4);
    k_cvt<<<1024, 256, 0, stream>>>(Whh[0], wbf + OW_WHH0, H4 * H / 4);
    k_cvt<<<1024, 256, 0, stream>>>(Wih[1], wbf + OW_WIH1, H4 * H / 4);
    k_cvt<<<1024, 256, 0, stream>>>(Whh[1], wbf + OW_WHH1, H4 * H / 4);
    k_cvt<<<1024, 256, 0, stream>>>(Wih[2], wbf + OW_WIH2, H4 * H / 4);
    k_cvt<<<1024, 256, 0, stream>>>(Whh[2], wbf + OW_WHH2, H4 * H / 4);
    k_cvt<<<2048, 256, 0, stream>>>(fcw, wbf + OW_FCW, V * H / 4);

    for (int t = 0; t < T; ++t) {
      const unsigned short* rb = hbf + (size_t)(t & 1) * (L * BH);       // read bank
      unsigned short* wb = hbf + (size_t)((t + 1) & 1) * (L * BH);      // write bank
      k_skinny_bf<<<H / 16, 256, 0, stream>>>(rb + 2 * BH, wbf + OW_WA, H, ba, qwa, H);
      k_scores<<<(B * S) / 4, 256, 0, stream>>>(qwa, ukeys, Va, vb, temp, vlen, sco);
      k_smctx<<<B, 256, 0, stream>>>(sco, enc, embbf + (size_t)t * BH, cng, cnb, xcbf,
                                     out + ATTN_OFF, t);
      k_gates4<<<H / 4, 256, 0, stream>>>(xcbf, H2, rb, H,
                                          wbf + OW_WIH0, wbf + OW_WHH0,
                                          bih[0], bhh[0], cst, hst, wb);
      k_gates4<<<H / 4, 256, 0, stream>>>(wb, H, rb + BH, H,
                                          wbf + OW_WIH1, wbf + OW_WHH1,
                                          bih[1], bhh[1], cst + BH, hst + BH, wb + BH);
      k_gates4<<<H / 4, 256, 0, stream>>>(wb + BH, H, rb + 2 * BH, H,
                                          wbf + OW_WIH2, wbf + OW_WHH2,
                                          bih[2], bhh[2], cst + 2 * BH,
                                          h2all + (size_t)t * BH, wb + 2 * BH);
    }
    k_ln_all<<<T * B, 256, 0, stream>>>(h2all, ong, onb, olall);
    k_gemm_logits<<<dim3(V / 128, (T * B) / 64), 256, 0, stream>>>(olall, wbf + OW_FCW,
                                                                   fcb, out);
    k_fin<<<768, 256, 0, stream>>>(hst, h2all + (size_t)(T - 1) * BH, cst, out);
  } else {
    // fallback: round-3 proven path (f32 weights, in-register conversion)
    for (int t = 0; t < T; ++t) {
      k_mfma_skinny<<<H / 16, 256, 0, stream>>>(hbf + 2 * BH, Wa, H, nullptr, nullptr, 0,
                                                ba, nullptr, qwa, H);
      k_scores<<<(B * S) / 4, 256, 0, stream>>>(qwa, ukeys, Va, vb, temp, vlen, sco);
      k_smctx<<<B, 256, 0, stream>>>(sco, enc, embbf + (size_t)t * BH, cng, cnb, xcbf,
                                     out + ATTN_OFF, t);
      k_mfma_skinny<<<H4 / 16, 256, 0, stream>>>(xcbf, Wih[0], H2, hbf, Whh[0], H,
                                                 bih[0], bhh[0], gat, H4);
      k_cell<<<BH / 256, 256, 0, stream>>>(gat, cst, hst, hbf);
      k_mfma_skinny<<<H4 / 16, 256, 0, stream>>>(hbf, Wih[1], H, hbf + BH, Whh[1], H,
                                                 bih[1], bhh[1], gat, H4);
      k_cell<<<BH / 256, 256, 0, stream>>>(gat, cst + BH, hst + BH, hbf + BH);
      k_mfma_skinny<<<H4 / 16, 256, 0, stream>>>(hbf + BH, Wih[2], H, hbf + 2 * BH, Whh[2], H,
                                                 bih[2], bhh[2], gat, H4);
      k_cell2ln<<<B, 256, 0, stream>>>(gat, cst + 2 * BH, hst + 2 * BH, ong, onb,
                                       olall + (size_t)t * BH, hbf + 2 * BH);
      k_mfma_skinny<<<V / 16, 256, 0, stream>>>(olall + (size_t)t * BH, fcw, H,
                                                nullptr, nullptr, 0,
                                                fcb, nullptr, out + (size_t)t * V, T * V);
    }
    k_fin<<<768, 256, 0, stream>>>(hst, hst + 2 * BH, cst, out);
  }
}